// Round 1
// baseline (1651.161 us; speedup 1.0000x reference)
//
#include <hip/hip_runtime.h>

// Problem constants (fixed by the reference)
#define N 2048
#define D 256
#define C 768          // 3*D
#define V 2
#define L 16
#define NSTATE 15      // S_0..S_14 (step-15 mask provably empty)
#define NAPP 14        // encoder applications
#define TCAP 256       // canonical masked-entry cap per variant (expected ~107)
#define FCAP 64        // follower cap per step (expected ~32)
#define NBLK 512       // persistent blocks in k_loop (co-resident: 3 blocks/CU cap)

typedef __attribute__((ext_vector_type(8))) short bf16x8;
typedef __attribute__((ext_vector_type(4))) float f32x4;

__device__ __forceinline__ ushort bf16_rn(float x) {
  unsigned u = __float_as_uint(x);
  u += 0x7FFFu + ((u >> 16) & 1u);
  return (ushort)(u >> 16);
}
__device__ __forceinline__ float bf16_f(ushort h) {
  return __uint_as_float(((unsigned)h) << 16);
}

// Chunk-tiled operand layouts (chunk = 32 rows x 64 k = 2048 ushorts = 4 KB).
__device__ __forceinline__ size_t a_addr(int row, int k) {
  return ((size_t)(row >> 5) * 4 + (k >> 6)) * 2048 + (row & 31) * 64 + (k & 63);
}
__device__ __forceinline__ size_t wt_addr(int n, int k) {
  return ((size_t)(n >> 5) * 4 + (k >> 6)) * 2048 + (n & 31) * 64 + (k & 63);
}

// ---------------------------------------------------------------------------
// k_init: states0 = emb; A0 bf16 split (chunked); Wt=[W_self|W_nbr]^T split
// (chunked); zero out / fillpos / barrier state.
// ---------------------------------------------------------------------------
__global__ __launch_bounds__(256) void k_init(
    const float* __restrict__ emb, const float* __restrict__ Ws,
    const float* __restrict__ Wn, float* __restrict__ states0,
    ushort* __restrict__ WtHi, ushort* __restrict__ WtLo,
    ushort* __restrict__ A0hi, ushort* __restrict__ A0lo,
    float* __restrict__ out, int* __restrict__ fillpos, int* __restrict__ bar) {
  size_t i = (size_t)blockIdx.x * 256 + threadIdx.x;
  size_t stride = (size_t)gridDim.x * 256;
  for (size_t x = i; x < (size_t)N * D; x += stride) {
    float v = emb[x];
    states0[x] = v;
    ushort h = bf16_rn(v);
    ushort l = bf16_rn(v - bf16_f(h));
    size_t a = a_addr((int)(x >> 8), (int)(x & 255));
    A0hi[a] = h;
    A0lo[a] = l;
  }
  for (size_t x = i; x < (size_t)512 * 256; x += stride) {
    int n = (int)(x >> 8), k = (int)(x & 255);
    float v = (n < 256) ? Ws[(size_t)k * 256 + n] : Wn[(size_t)k * 256 + (n - 256)];
    ushort h = bf16_rn(v);
    size_t a = wt_addr(n, k);
    WtHi[a] = h;
    WtLo[a] = bf16_rn(v - bf16_f(h));
  }
  for (size_t x = i; x < (size_t)N * C; x += stride) out[x] = 0.f;
  for (size_t x = i; x < N; x += stride) fillpos[x] = 0;
  if (i < 2) bar[i] = 0;
}

// ---------------------------------------------------------------------------
// k_degA: fused k_deg (blocks 0..127) + k_metaA (blocks 128..159).
// ---------------------------------------------------------------------------
__global__ __launch_bounds__(256) void k_degA(
    const int* __restrict__ ei, int E, int* __restrict__ fillpos,
    const int* __restrict__ adj, const int* __restrict__ variants,
    int* __restrict__ stepP, int* __restrict__ stepDm,
    int* __restrict__ stepCnt, int* __restrict__ hasG, int* __restrict__ tlG) {
  __shared__ int tl_sh[16];
  __shared__ int foll[FCAP], fbits[FCAP];
  __shared__ int sh_tc, sh_fcnt, sh_ecnt;
  int t = threadIdx.x;
  if (blockIdx.x < 128) {
    for (int e = blockIdx.x * 256 + t; e < E; e += 128 * 256)
      atomicAdd(&fillpos[ei[E + e]], 1);
    return;
  }
  int vi = blockIdx.x - 128;
  int v = vi / L, i = vi % L;
  int a = variants[vi];
  if (t == 0) {
    int cnt = 0;
    for (int j = i + 1; j < L; j++) {
      int x = variants[v * L + j];
      bool dup = false;
      for (int q = 0; q < cnt; q++) if (tl_sh[q] == x) dup = true;
      if (!dup) tl_sh[cnt++] = x;
    }
    sh_tc = cnt;
    sh_fcnt = 0;
    sh_ecnt = 0;
    for (int q = 0; q < cnt; q++) tlG[vi * 16 + q] = tl_sh[q];
  }
  __syncthreads();
  for (int p = t; p < N; p += 256) {
    if (adj[(size_t)a * N + p] != 0) {
      int f = atomicAdd(&sh_fcnt, 1);
      if (f < FCAP) foll[f] = p;
    }
  }
  __syncthreads();
  int fc = sh_fcnt < FCAP ? sh_fcnt : FCAP;
  int tc = sh_tc;
  for (int x = t; x < fc; x += 256) fbits[x] = 0;
  __syncthreads();
  for (int x = t; x < fc * tc; x += 256) {
    int fi = x / tc, q = x - fi * tc;
    if (adj[(size_t)foll[fi] * N + tl_sh[q]] != 0) atomicOr(&fbits[fi], 1 << q);
  }
  __syncthreads();
  for (int fi = t; fi < fc; fi += 256) {
    int bits = fbits[fi];
    if (bits) {
      int e = atomicAdd(&sh_ecnt, 1);
      stepP[vi * FCAP + e] = foll[fi];
      stepDm[vi * FCAP + e] = bits;
    }
  }
  __syncthreads();
  if (t == 0) {
    stepCnt[vi] = sh_ecnt;
    hasG[vi] = (sh_fcnt > 0);
  }
}

// ---------------------------------------------------------------------------
// k_scan: exclusive prefix over degrees -> row_ptr; resets fillpos to starts.
// ---------------------------------------------------------------------------
__global__ __launch_bounds__(256) void k_scan(int* __restrict__ fillpos,
                                              int* __restrict__ row_ptr) {
  __shared__ int part[256];
  __shared__ int base[257];
  int t = threadIdx.x;
  int v[8];
  int s = 0;
  for (int j = 0; j < 8; j++) { v[j] = fillpos[t * 8 + j]; s += v[j]; }
  part[t] = s;
  __syncthreads();
  if (t == 0) {
    int acc = 0;
    for (int q = 0; q < 256; q++) { base[q] = acc; acc += part[q]; }
    base[256] = acc;
  }
  __syncthreads();
  int acc = base[t];
  for (int j = 0; j < 8; j++) {
    row_ptr[t * 8 + j] = acc;
    fillpos[t * 8 + j] = acc;
    acc += v[j];
  }
  if (t == 255) row_ptr[N] = base[256];
}

// ---------------------------------------------------------------------------
// k_fillB: fused k_fill (blocks 0..127) + k_metaB (blocks 128..128+V-1).
// ---------------------------------------------------------------------------
__global__ __launch_bounds__(256) void k_fillB(
    const int* __restrict__ ei, int E, int* __restrict__ fillpos,
    int* __restrict__ csr_src,
    const int* __restrict__ stepP, const int* __restrict__ stepDm,
    const int* __restrict__ stepCnt, const int* __restrict__ hasG,
    int* __restrict__ entP, int* __restrict__ entPrev, int* __restrict__ entDm,
    int* __restrict__ offsG, int* __restrict__ kidxG, int* __restrict__ cmatG,
    int* __restrict__ lastPG, int* __restrict__ lastIG, int* __restrict__ lastMG,
    int* __restrict__ cntG) {
  __shared__ int pmask[N];           // 8 KB
  __shared__ int sP[16][FCAP];       // 4 KB
  __shared__ int sDm[16][FCAP];      // 4 KB
  __shared__ int cnt[16], offs[17];
  __shared__ int cmat_sh[256];       // 1 KB
  __shared__ int sh_u;
  int t = threadIdx.x;
  if (blockIdx.x < 128) {
    for (int e = blockIdx.x * 256 + t; e < E; e += 128 * 256) {
      int dst = ei[E + e];
      int pos = atomicAdd(&fillpos[dst], 1);
      csr_src[pos] = ei[e];
    }
    return;
  }
  int v = blockIdx.x - 128;
  for (int p = t; p < N; p += 256) pmask[p] = 0;
  for (int x = t; x < 256; x += 256) cmat_sh[x] = 0;
  if (t < 16) cnt[t] = stepCnt[v * L + t];
  if (t == 0) sh_u = 0;
  __syncthreads();
  if (t == 0) {
    int acc = 0;
    for (int i = 0; i < 16; i++) {
      offs[i] = acc < TCAP ? acc : TCAP;
      acc += cnt[i];
    }
    offs[16] = acc < TCAP ? acc : TCAP;
    cntG[v * 2 + 0] = offs[16];
    int k = 0;
    for (int i = 0; i < L; i++) {
      kidxG[v * 16 + i] = k;
      if (hasG[v * L + i]) k++;
    }
  }
  for (int x = t; x < 16 * FCAP; x += 256) {
    int i = x >> 6, f = x & 63;
    if (f < stepCnt[v * L + i]) {
      int p = stepP[(v * L + i) * FCAP + f];
      sP[i][f] = p;
      sDm[i][f] = stepDm[(v * L + i) * FCAP + f];
      atomicOr(&pmask[p], 1 << i);
    }
  }
  __syncthreads();
  for (int x = t; x < 16 * FCAP; x += 256) {
    int i = x >> 6, f = x & 63;
    if (f < cnt[i]) {
      int e = offs[i] + f;
      if (e < TCAP) {
        int p = sP[i][f];
        entP[v * TCAP + e] = p;
        entDm[v * TCAP + e] = sDm[i][f];
        int m = pmask[p] & ((1 << i) - 1);
        int prev = -1;
        if (m) {
          int j = 31 - __clz(m);
          int cj = cnt[j];
          for (int f2 = 0; f2 < cj; f2++)
            if (sP[j][f2] == p) { prev = offs[j] + f2; break; }
        }
        entPrev[v * TCAP + e] = prev;
      }
    }
  }
  __syncthreads();
  for (int p = t; p < N; p += 256) {
    int m = pmask[p];
    if (m) {
      int u = atomicAdd(&sh_u, 1);
      int j = 31 - __clz(m);
      int li = -1;
      int cj = cnt[j];
      for (int f2 = 0; f2 < cj; f2++)
        if (sP[j][f2] == p) { li = offs[j] + f2; break; }
      lastPG[v * TCAP + u] = p;
      lastIG[v * TCAP + u] = li;
      lastMG[v * TCAP + u] = m;
      int mm = m;
      while (mm) {
        int bi = __ffs(mm) - 1; mm &= mm - 1;
        int m2 = m & ((1 << bi) - 1);
        while (m2) {
          int bj = __ffs(m2) - 1; m2 &= m2 - 1;
          atomicAdd(&cmat_sh[bi * 16 + bj], 1);
        }
      }
    }
  }
  __syncthreads();
  if (t == 0) cntG[v * 2 + 1] = sh_u;
  for (int x = t; x < 256; x += 256) cmatG[v * 256 + x] = cmat_sh[x];
  for (int x = t; x < 17; x += 256) offsG[v * 17 + x] = offs[x];
}

// ---------------------------------------------------------------------------
// gbar: grid-wide generation barrier (agent scope).  Acquire/release atomics
// emit the L2 writeback/invalidate needed for cross-XCD visibility; this is
// the same flush a kernel boundary performs, without the launch.
// ---------------------------------------------------------------------------
__device__ __forceinline__ void gbar(int* bar, int& gen) {
  __syncthreads();
  if (threadIdx.x == 0) {
    int target = ++gen;
    if (__hip_atomic_fetch_add(&bar[0], 1, __ATOMIC_ACQ_REL,
                               __HIP_MEMORY_SCOPE_AGENT) == NBLK - 1) {
      __hip_atomic_store(&bar[0], 0, __ATOMIC_RELAXED, __HIP_MEMORY_SCOPE_AGENT);
      __hip_atomic_store(&bar[1], target, __ATOMIC_RELEASE,
                         __HIP_MEMORY_SCOPE_AGENT);
    } else {
      while (__hip_atomic_load(&bar[1], __ATOMIC_RELAXED,
                               __HIP_MEMORY_SCOPE_AGENT) < target)
        __builtin_amdgcn_s_sleep(2);
      (void)__hip_atomic_load(&bar[1], __ATOMIC_ACQUIRE,
                              __HIP_MEMORY_SCOPE_AGENT);
    }
  }
  __syncthreads();
}

// ---------------------------------------------------------------------------
// k_loop: persistent fused iteration kernel.  512 blocks x 256 threads.
// Per block: one 32-row A tile x 64 output cols (W-hi in regs, W-lo in LDS,
// both loaded ONCE for all 14 iterations); then 4 comb rows (1/wave).
// 27 grid barriers replace 28 kernel launches.
// ---------------------------------------------------------------------------
__global__ __launch_bounds__(256, 2) void k_loop(
    ushort* __restrict__ A0h, ushort* __restrict__ A0l,
    ushort* __restrict__ A1h, ushort* __restrict__ A1l,
    const ushort* __restrict__ WtHi, const ushort* __restrict__ WtLo,
    float* __restrict__ Z, const float* __restrict__ bias,
    const int* __restrict__ row_ptr, const int* __restrict__ csr_src,
    float* __restrict__ states, int* bar) {
  __shared__ __align__(16) ushort Ash[2][32][72], Asl[2][32][72];  // 18.4 KB
  __shared__ __align__(16) ushort Wsl[64][264];                    // 33.8 KB
  const int tid = threadIdx.x, wave = tid >> 6, lane = tid & 63;
  const int quad = lane >> 4, l16 = lane & 15;
  const int wr = wave >> 1, wc = wave & 1;
  const int b = blockIdx.x;
  const int mb = b >> 3, nbp = b & 7;
  const int sr = tid >> 3, sc = (tid & 7) * 8;

  // Stage W-lo (64 n-rows x 256 k) into LDS once for the whole kernel.
#pragma unroll
  for (int cc = 0; cc < 8; cc++) {
    uint4 r = *(const uint4*)&WtLo[((size_t)nbp * 8 + cc) * 2048 + tid * 8];
    *(uint4*)&Wsl[(cc >> 2) * 32 + sr][(cc & 3) * 64 + sc] = r;
  }
  // W-hi fragments in registers: two 16-col groups per wave, full K=256.
  bf16x8 wh0[8], wh1[8];
  {
    const int rr = wc * 16 + l16;
#pragma unroll
    for (int kf8 = 0; kf8 < 8; kf8++) {
      size_t ko = (size_t)(kf8 & 1) * 32 + quad * 8;
      wh0[kf8] = *(const bf16x8*)
          &WtHi[((size_t)(nbp * 2 + 0) * 4 + (kf8 >> 1)) * 2048 + rr * 64 + ko];
      wh1[kf8] = *(const bf16x8*)
          &WtHi[((size_t)(nbp * 2 + 1) * 4 + (kf8 >> 1)) * 2048 + rr * 64 + ko];
    }
  }
  const float4 bv = ((const float4*)bias)[lane];
  const int crow = b * 4 + wave;
  const int ce0 = row_ptr[crow], ce1 = row_ptr[crow + 1];
  int gen = 0;
  if (tid == 0)  // replay-robust: barrier generations relative to entry value
    gen = __hip_atomic_load(&bar[1], __ATOMIC_RELAXED, __HIP_MEMORY_SCOPE_AGENT);

  const size_t abase = (size_t)mb * 8192 + tid * 8;
#pragma unroll 1
  for (int it = 0; it < NAPP; it++) {
    const ushort* Ah = (it & 1) ? A1h : A0h;
    const ushort* Al = (it & 1) ? A1l : A0l;
    ushort* NAh = (it & 1) ? A0h : A1h;
    ushort* NAl = (it & 1) ? A0l : A1l;
    // ------------- GEMM phase: Z[32 rows x 64 cols] -------------
    f32x4 acc0 = {0.f, 0.f, 0.f, 0.f}, acc1 = {0.f, 0.f, 0.f, 0.f};
    {
      uint4 ra = *(const uint4*)&Ah[abase];
      uint4 rl = *(const uint4*)&Al[abase];
      *(uint4*)&Ash[0][sr][sc] = ra;
      *(uint4*)&Asl[0][sr][sc] = rl;
    }
    __syncthreads();
#pragma unroll
    for (int c = 0; c < 4; c++) {
      const int rb = c & 1;
      uint4 ra, rl;
      if (c < 3) {
        ra = *(const uint4*)&Ah[abase + (size_t)(c + 1) * 2048];
        rl = *(const uint4*)&Al[abase + (size_t)(c + 1) * 2048];
      }
#pragma unroll
      for (int kf = 0; kf < 2; kf++) {
        const int ko = kf * 32 + quad * 8;
        bf16x8 a_h = *(const bf16x8*)&Ash[rb][wr * 16 + l16][ko];
        bf16x8 a_l = *(const bf16x8*)&Asl[rb][wr * 16 + l16][ko];
        bf16x8 wl0 = *(const bf16x8*)&Wsl[wc * 16 + l16][c * 64 + ko];
        bf16x8 wl1 = *(const bf16x8*)&Wsl[32 + wc * 16 + l16][c * 64 + ko];
        acc0 = __builtin_amdgcn_mfma_f32_16x16x32_bf16(a_h, wh0[c * 2 + kf], acc0, 0, 0, 0);
        acc0 = __builtin_amdgcn_mfma_f32_16x16x32_bf16(a_h, wl0, acc0, 0, 0, 0);
        acc0 = __builtin_amdgcn_mfma_f32_16x16x32_bf16(a_l, wh0[c * 2 + kf], acc0, 0, 0, 0);
        acc1 = __builtin_amdgcn_mfma_f32_16x16x32_bf16(a_h, wh1[c * 2 + kf], acc1, 0, 0, 0);
        acc1 = __builtin_amdgcn_mfma_f32_16x16x32_bf16(a_h, wl1, acc1, 0, 0, 0);
        acc1 = __builtin_amdgcn_mfma_f32_16x16x32_bf16(a_l, wh1[c * 2 + kf], acc1, 0, 0, 0);
      }
      if (c < 3) {
        const int wb2 = rb ^ 1;
        *(uint4*)&Ash[wb2][sr][sc] = ra;
        *(uint4*)&Asl[wb2][sr][sc] = rl;
        __syncthreads();
      }
    }
    {
      const int col0 = nbp * 64 + wc * 16 + l16;
      const int row0 = mb * 32 + wr * 16 + quad * 4;
#pragma unroll
      for (int r = 0; r < 4; r++) {
        Z[(size_t)(row0 + r) * 512 + col0] = acc0[r];
        Z[(size_t)(row0 + r) * 512 + col0 + 32] = acc1[r];
      }
    }
    gbar(bar, gen);   // Z visible everywhere
    // ------------- comb phase: 1 row per wave -------------
    {
      const float4* Zp = (const float4*)Z;
      float4 a1 = Zp[(size_t)crow * 128 + lane];   // Z1 self
      float4 a2 = {0.f, 0.f, 0.f, 0.f};
      int e = ce0;
      for (; e + 1 < ce1; e += 2) {
        int s0 = csr_src[e], s1 = csr_src[e + 1];
        float4 x0 = Zp[(size_t)s0 * 128 + 64 + lane];
        float4 x1 = Zp[(size_t)s1 * 128 + 64 + lane];
        a1.x += x0.x; a1.y += x0.y; a1.z += x0.z; a1.w += x0.w;
        a2.x += x1.x; a2.y += x1.y; a2.z += x1.z; a2.w += x1.w;
      }
      if (e < ce1) {
        float4 x0 = Zp[(size_t)csr_src[e] * 128 + 64 + lane];
        a1.x += x0.x; a1.y += x0.y; a1.z += x0.z; a1.w += x0.w;
      }
      float v0 = fmaxf(a1.x + a2.x + bv.x, 0.f);
      float v1 = fmaxf(a1.y + a2.y + bv.y, 0.f);
      float v2 = fmaxf(a1.z + a2.z + bv.z, 0.f);
      float v3 = fmaxf(a1.w + a2.w + bv.w, 0.f);
      float* stnext = states + (size_t)(it + 1) * N * D;
      *(float4*)(stnext + (size_t)crow * D + lane * 4) = make_float4(v0, v1, v2, v3);
      ushort h0 = bf16_rn(v0), h1 = bf16_rn(v1), h2 = bf16_rn(v2), h3 = bf16_rn(v3);
      size_t ca = a_addr(crow, lane * 4);
      *(ushort4*)&NAh[ca] = make_ushort4(h0, h1, h2, h3);
      *(ushort4*)&NAl[ca] = make_ushort4(
          bf16_rn(v0 - bf16_f(h0)), bf16_rn(v1 - bf16_f(h1)),
          bf16_rn(v2 - bf16_f(h2)), bf16_rn(v3 - bf16_f(h3)));
    }
    if (it < NAPP - 1) gbar(bar, gen);   // A[nxt] visible before next GEMM
  }
}

// ---------------------------------------------------------------------------
// k_pi: LINEAR reformulation, now 256 threads/block (4 waves).
// cat-fill entries split across waves; prefix done per place-chain in
// parallel (chains avg length ~1); per-step sums + output loop wave-parallel;
// only the 16-step S recurrence stays on wave 0.
// ---------------------------------------------------------------------------
#define PI_LDS_BYTES (TCAP * 64 * 4 + 16 * 64 * 4 + 16 * 64 * 4 + 256 * 4 + \
                      3 * TCAP * 4 + 17 * 4 + 16 * 4 + 256 * 4)
__global__ __launch_bounds__(256) void k_pi(
    const float* __restrict__ states, float* __restrict__ out,
    const int* __restrict__ variants,
    const int* __restrict__ entP, const int* __restrict__ entPrev,
    const int* __restrict__ entDm, const int* __restrict__ offsG,
    const int* __restrict__ kidxG, const int* __restrict__ tlG,
    const int* __restrict__ cmatG, const int* __restrict__ lastPG,
    const int* __restrict__ lastIG, const int* __restrict__ lastMG,
    const int* __restrict__ cntG) {
  extern __shared__ __align__(16) float smf[];
  float* catb = smf;                       // [TCAP][64]  (becomes pref)
  float* S_lds = catb + TCAP * 64;         // [16][64]
  float* aS = S_lds + 16 * 64;             // [16][64] per-step sums
  float* cmatf = aS + 16 * 64;             // [256]
  int* eP  = (int*)(cmatf + 256);          // [TCAP]
  int* ePr = eP + TCAP;
  int* eDm = ePr + TCAP;
  int* offs = eDm + TCAP;                  // [17]
  int* kidx = offs + 17;                   // [16]
  int* tl = kidx + 16;                     // [256]
  int v = blockIdx.x / 12, cgi = blockIdx.x % 12;
  int grp = cgi >> 2;
  int tid = threadIdx.x, lane = tid & 63, w = tid >> 6;
  int cl = (cgi & 3) * 64 + lane;          // 0..255 within third
  int col = cgi * 64 + lane;               // 0..767

  int T = cntG[v * 2 + 0], U = cntG[v * 2 + 1];
  for (int x = tid; x < T; x += 256) {
    eP[x] = entP[v * TCAP + x];
    ePr[x] = entPrev[v * TCAP + x];
    eDm[x] = entDm[v * TCAP + x];
  }
  for (int x = tid; x < 17; x += 256) offs[x] = offsG[v * 17 + x];
  if (tid < 16) kidx[tid] = kidxG[v * 16 + tid];
  for (int x = tid; x < 256; x += 256) {
    tl[x] = tlG[v * 256 + x];
    cmatf[x] = (float)cmatG[v * 256 + x];
  }
  __syncthreads();

  // cat fill: waves split the entries of each step
  for (int i = 0; i < L; i++) {
    int kk = kidx[i]; if (kk > NSTATE - 1) kk = NSTATE - 1;
    const float* embS = states + (size_t)kk * N * D;
    int o0 = offs[i], o1 = offs[i + 1];
    if (grp == 0) {
      for (int e = o0 + w; e < o1; e += 4)
        catb[e * 64 + lane] = embS[(size_t)eP[e] * D + cl];
    } else if (grp == 1) {
      float embA = embS[(size_t)variants[v * L + i] * D + cl];
      for (int e = o0 + w; e < o1; e += 4) catb[e * 64 + lane] = embA;
    } else {
      for (int e = o0 + w; e < o1; e += 4) {
        float sa = 0.f;
        int bm = eDm[e];
        while (bm) {
          int q = __ffs(bm) - 1; bm &= bm - 1;
          sa += embS[(size_t)tl[i * 16 + q] * D + cl];
        }
        catb[e * 64 + lane] = sa;
      }
    }
  }
  __syncthreads();
  // prefix over place-chains, chains distributed across waves
  for (int u = w; u < U; u += 4) {
    int li = lastIG[v * TCAP + u];
    int len = 0;
    for (int c2 = li; c2 >= 0; c2 = ePr[c2]) len++;
    for (int j = 1; j < len; j++) {        // root -> last order
      int c2 = li;
      for (int k = 0; k < len - 1 - j; k++) c2 = ePr[c2];
      catb[c2 * 64 + lane] += catb[ePr[c2] * 64 + lane];
    }
  }
  __syncthreads();
  // per-step sums of pref
  for (int i = w; i < 16; i += 4) {
    float a = 0.f;
    for (int e = offs[i]; e < offs[i + 1]; e++) a += catb[e * 64 + lane];
    aS[i * 64 + lane] = a;
  }
  __syncthreads();
  // S recurrence (serial over 16 steps, wave 0)
  if (w == 0) {
    float S[16];
    float Sp = 0.f;
#pragma unroll
    for (int i = 0; i < 16; i++) {
      float sv = Sp + aS[i * 64 + lane];
#pragma unroll
      for (int j = 0; j < 16; j++)
        if (j < i) sv += cmatf[i * 16 + j] * S[j];
      S[i] = sv;
      S_lds[i * 64 + lane] = sv;
      Sp = sv;
    }
  }
  __syncthreads();
  // outputs, places distributed across waves
  for (int u = w; u < U; u += 4) {
    int p = lastPG[v * TCAP + u];
    int li = lastIG[v * TCAP + u];
    int m = lastMG[v * TCAP + u];
    float acc = catb[li * 64 + lane];
    while (m) {
      int q = __ffs(m) - 1; m &= m - 1;
      acc += S_lds[q * 64 + lane];
    }
    atomicAdd(&out[(size_t)p * C + col], acc);
  }
}

// ---------------------------------------------------------------------------
extern "C" void kernel_launch(void* const* d_in, const int* in_sizes, int n_in,
                              void* d_out, int out_size, void* d_ws, size_t ws_size,
                              hipStream_t stream) {
  const float* emb      = (const float*)d_in[0];
  const float* Ws       = (const float*)d_in[1];
  const float* Wn       = (const float*)d_in[2];
  const float* bias     = (const float*)d_in[3];
  const int*   variants = (const int*)d_in[4];
  const int*   adj      = (const int*)d_in[5];
  const int*   ei       = (const int*)d_in[6];
  const int    E        = in_sizes[6] / 2;
  float* out            = (float*)d_out;

  char* base = (char*)d_ws;
  float* states = (float*)base;            base += (size_t)NSTATE * N * D * 4;
  float* Z      = (float*)base;            base += (size_t)N * 512 * 4;
  ushort* WtHi  = (ushort*)base;           base += (size_t)512 * 256 * 2;
  ushort* WtLo  = (ushort*)base;           base += (size_t)512 * 256 * 2;
  ushort* A0h   = (ushort*)base;           base += (size_t)N * D * 2;
  ushort* A0l   = (ushort*)base;           base += (size_t)N * D * 2;
  ushort* A1h   = (ushort*)base;           base += (size_t)N * D * 2;
  ushort* A1l   = (ushort*)base;           base += (size_t)N * D * 2;
  int* row_ptr  = (int*)base;              base += (N + 1) * 4;
  int* fillpos  = (int*)base;              base += N * 4;
  int* csr_src  = (int*)base;              base += (size_t)E * 4;
  int* stepP    = (int*)base;              base += V * L * FCAP * 4;
  int* stepDm   = (int*)base;              base += V * L * FCAP * 4;
  int* stepCnt  = (int*)base;              base += V * L * 4;
  int* hasG     = (int*)base;              base += V * L * 4;
  int* entP     = (int*)base;              base += V * TCAP * 4;
  int* entPrev  = (int*)base;              base += V * TCAP * 4;
  int* entDm    = (int*)base;              base += V * TCAP * 4;
  int* offsG    = (int*)base;              base += V * 17 * 4;
  int* kidxG    = (int*)base;              base += V * 16 * 4;
  int* tlG      = (int*)base;              base += V * 256 * 4;
  int* cmatG    = (int*)base;              base += V * 256 * 4;
  int* lastPG   = (int*)base;              base += V * TCAP * 4;
  int* lastIG   = (int*)base;              base += V * TCAP * 4;
  int* lastMG   = (int*)base;              base += V * TCAP * 4;
  int* cntG     = (int*)base;              base += V * 2 * 4;
  int* bar      = (int*)base;              base += 2 * 4;

  hipFuncSetAttribute((const void*)k_pi,
                      hipFuncAttributeMaxDynamicSharedMemorySize, PI_LDS_BYTES);

  k_init<<<512, 256, 0, stream>>>(emb, Ws, Wn, states, WtHi, WtLo, A0h, A0l,
                                  out, fillpos, bar);
  k_degA<<<128 + V * L, 256, 0, stream>>>(ei, E, fillpos, adj, variants,
                                          stepP, stepDm, stepCnt, hasG, tlG);
  k_scan<<<1, 256, 0, stream>>>(fillpos, row_ptr);
  k_fillB<<<128 + V, 256, 0, stream>>>(ei, E, fillpos, csr_src, stepP, stepDm,
                                       stepCnt, hasG, entP, entPrev, entDm,
                                       offsG, kidxG, cmatG, lastPG, lastIG,
                                       lastMG, cntG);
  k_loop<<<NBLK, 256, 0, stream>>>(A0h, A0l, A1h, A1l, WtHi, WtLo, Z, bias,
                                   row_ptr, csr_src, states, bar);
  k_pi<<<V * 12, 256, PI_LDS_BYTES, stream>>>(states, out, variants, entP,
                                              entPrev, entDm, offsG, kidxG, tlG,
                                              cmatG, lastPG, lastIG, lastMG,
                                              cntG);
}

// Round 2
// 484.484 us; speedup vs baseline: 3.4081x; 3.4081x over previous
//
#include <hip/hip_runtime.h>

// Problem constants (fixed by the reference)
#define N 2048
#define D 256
#define C 768          // 3*D
#define V 2
#define L 16
#define NSTATE 15      // S_0..S_14 (step-15 mask provably empty)
#define NAPP 14        // encoder applications
#define TCAP 256       // canonical masked-entry cap per variant (expected ~107)
#define FCAP 64        // follower cap per step (expected ~32)

typedef __attribute__((ext_vector_type(8))) short bf16x8;
typedef __attribute__((ext_vector_type(4))) float f32x4;

__device__ __forceinline__ ushort bf16_rn(float x) {
  unsigned u = __float_as_uint(x);
  u += 0x7FFFu + ((u >> 16) & 1u);
  return (ushort)(u >> 16);
}
__device__ __forceinline__ float bf16_f(ushort h) {
  return __uint_as_float(((unsigned)h) << 16);
}

// A chunk-tiled layout (chunk = 32 rows x 64 k = 2048 ushorts = 4 KB); k<256.
__device__ __forceinline__ size_t a_addr(int row, int k) {
  return ((size_t)(row >> 5) * 4 + (k >> 6)) * 2048 + (row & 31) * 64 + (k & 63);
}
// W2 layout: [n=256 output cols][k=512 input dims], chunked 32n x 64k.
__device__ __forceinline__ size_t wt_addr(int n, int k) {
  return ((size_t)(n >> 5) * 8 + (k >> 6)) * 2048 + (n & 31) * 64 + (k & 63);
}

// ---------------------------------------------------------------------------
// k_init: states0 = emb; A0 bf16 split (chunked); W2=[W_self;W_nbr] as
// [n][k=512] bf16 split (chunked); zero out / fillpos.
// ---------------------------------------------------------------------------
__global__ __launch_bounds__(256) void k_init(
    const float* __restrict__ emb, const float* __restrict__ Ws,
    const float* __restrict__ Wn, float* __restrict__ states0,
    ushort* __restrict__ W2h, ushort* __restrict__ W2l,
    ushort* __restrict__ A0hi, ushort* __restrict__ A0lo,
    float* __restrict__ out, int* __restrict__ fillpos) {
  size_t i = (size_t)blockIdx.x * 256 + threadIdx.x;
  size_t stride = (size_t)gridDim.x * 256;
  for (size_t x = i; x < (size_t)N * D; x += stride) {
    float v = emb[x];
    states0[x] = v;
    ushort h = bf16_rn(v);
    ushort l = bf16_rn(v - bf16_f(h));
    size_t a = a_addr((int)(x >> 8), (int)(x & 255));
    A0hi[a] = h;
    A0lo[a] = l;
  }
  for (size_t x = i; x < (size_t)256 * 512; x += stride) {
    int n = (int)(x >> 9), k = (int)(x & 511);
    float v = (k < 256) ? Ws[(size_t)k * 256 + n]
                        : Wn[(size_t)(k - 256) * 256 + n];
    ushort h = bf16_rn(v);
    size_t a = wt_addr(n, k);
    W2h[a] = h;
    W2l[a] = bf16_rn(v - bf16_f(h));
  }
  for (size_t x = i; x < (size_t)N * C; x += stride) out[x] = 0.f;
  for (size_t x = i; x < N; x += stride) fillpos[x] = 0;
}

// ---------------------------------------------------------------------------
// k_degA: fused k_deg (blocks 0..127) + k_metaA (blocks 128..159).
// ---------------------------------------------------------------------------
__global__ __launch_bounds__(256) void k_degA(
    const int* __restrict__ ei, int E, int* __restrict__ fillpos,
    const int* __restrict__ adj, const int* __restrict__ variants,
    int* __restrict__ stepP, int* __restrict__ stepDm,
    int* __restrict__ stepCnt, int* __restrict__ hasG, int* __restrict__ tlG) {
  __shared__ int tl_sh[16];
  __shared__ int foll[FCAP], fbits[FCAP];
  __shared__ int sh_tc, sh_fcnt, sh_ecnt;
  int t = threadIdx.x;
  if (blockIdx.x < 128) {
    for (int e = blockIdx.x * 256 + t; e < E; e += 128 * 256)
      atomicAdd(&fillpos[ei[E + e]], 1);
    return;
  }
  int vi = blockIdx.x - 128;
  int v = vi / L, i = vi % L;
  int a = variants[vi];
  if (t == 0) {
    int cnt = 0;
    for (int j = i + 1; j < L; j++) {
      int x = variants[v * L + j];
      bool dup = false;
      for (int q = 0; q < cnt; q++) if (tl_sh[q] == x) dup = true;
      if (!dup) tl_sh[cnt++] = x;
    }
    sh_tc = cnt;
    sh_fcnt = 0;
    sh_ecnt = 0;
    for (int q = 0; q < cnt; q++) tlG[vi * 16 + q] = tl_sh[q];
  }
  __syncthreads();
  for (int p = t; p < N; p += 256) {
    if (adj[(size_t)a * N + p] != 0) {
      int f = atomicAdd(&sh_fcnt, 1);
      if (f < FCAP) foll[f] = p;
    }
  }
  __syncthreads();
  int fc = sh_fcnt < FCAP ? sh_fcnt : FCAP;
  int tc = sh_tc;
  for (int x = t; x < fc; x += 256) fbits[x] = 0;
  __syncthreads();
  for (int x = t; x < fc * tc; x += 256) {
    int fi = x / tc, q = x - fi * tc;
    if (adj[(size_t)foll[fi] * N + tl_sh[q]] != 0) atomicOr(&fbits[fi], 1 << q);
  }
  __syncthreads();
  for (int fi = t; fi < fc; fi += 256) {
    int bits = fbits[fi];
    if (bits) {
      int e = atomicAdd(&sh_ecnt, 1);
      stepP[vi * FCAP + e] = foll[fi];
      stepDm[vi * FCAP + e] = bits;
    }
  }
  __syncthreads();
  if (t == 0) {
    stepCnt[vi] = sh_ecnt;
    hasG[vi] = (sh_fcnt > 0);
  }
}

// ---------------------------------------------------------------------------
// k_scan: exclusive prefix over degrees -> row_ptr; resets fillpos to starts.
// ---------------------------------------------------------------------------
__global__ __launch_bounds__(256) void k_scan(int* __restrict__ fillpos,
                                              int* __restrict__ row_ptr) {
  __shared__ int part[256];
  __shared__ int base[257];
  int t = threadIdx.x;
  int v[8];
  int s = 0;
  for (int j = 0; j < 8; j++) { v[j] = fillpos[t * 8 + j]; s += v[j]; }
  part[t] = s;
  __syncthreads();
  if (t == 0) {
    int acc = 0;
    for (int q = 0; q < 256; q++) { base[q] = acc; acc += part[q]; }
    base[256] = acc;
  }
  __syncthreads();
  int acc = base[t];
  for (int j = 0; j < 8; j++) {
    row_ptr[t * 8 + j] = acc;
    fillpos[t * 8 + j] = acc;
    acc += v[j];
  }
  if (t == 255) row_ptr[N] = base[256];
}

// ---------------------------------------------------------------------------
// k_fillB: fused k_fill (blocks 0..127) + k_metaB (blocks 128..128+V-1).
// ---------------------------------------------------------------------------
__global__ __launch_bounds__(256) void k_fillB(
    const int* __restrict__ ei, int E, int* __restrict__ fillpos,
    int* __restrict__ csr_src,
    const int* __restrict__ stepP, const int* __restrict__ stepDm,
    const int* __restrict__ stepCnt, const int* __restrict__ hasG,
    int* __restrict__ entP, int* __restrict__ entPrev, int* __restrict__ entDm,
    int* __restrict__ offsG, int* __restrict__ kidxG, int* __restrict__ cmatG,
    int* __restrict__ lastPG, int* __restrict__ lastIG, int* __restrict__ lastMG,
    int* __restrict__ cntG) {
  __shared__ int pmask[N];           // 8 KB
  __shared__ int sP[16][FCAP];       // 4 KB
  __shared__ int sDm[16][FCAP];      // 4 KB
  __shared__ int cnt[16], offs[17];
  __shared__ int cmat_sh[256];       // 1 KB
  __shared__ int sh_u;
  int t = threadIdx.x;
  if (blockIdx.x < 128) {
    for (int e = blockIdx.x * 256 + t; e < E; e += 128 * 256) {
      int dst = ei[E + e];
      int pos = atomicAdd(&fillpos[dst], 1);
      csr_src[pos] = ei[e];
    }
    return;
  }
  int v = blockIdx.x - 128;
  for (int p = t; p < N; p += 256) pmask[p] = 0;
  for (int x = t; x < 256; x += 256) cmat_sh[x] = 0;
  if (t < 16) cnt[t] = stepCnt[v * L + t];
  if (t == 0) sh_u = 0;
  __syncthreads();
  if (t == 0) {
    int acc = 0;
    for (int i = 0; i < 16; i++) {
      offs[i] = acc < TCAP ? acc : TCAP;
      acc += cnt[i];
    }
    offs[16] = acc < TCAP ? acc : TCAP;
    cntG[v * 2 + 0] = offs[16];
    int k = 0;
    for (int i = 0; i < L; i++) {
      kidxG[v * 16 + i] = k;
      if (hasG[v * L + i]) k++;
    }
  }
  for (int x = t; x < 16 * FCAP; x += 256) {
    int i = x >> 6, f = x & 63;
    if (f < stepCnt[v * L + i]) {
      int p = stepP[(v * L + i) * FCAP + f];
      sP[i][f] = p;
      sDm[i][f] = stepDm[(v * L + i) * FCAP + f];
      atomicOr(&pmask[p], 1 << i);
    }
  }
  __syncthreads();
  for (int x = t; x < 16 * FCAP; x += 256) {
    int i = x >> 6, f = x & 63;
    if (f < cnt[i]) {
      int e = offs[i] + f;
      if (e < TCAP) {
        int p = sP[i][f];
        entP[v * TCAP + e] = p;
        entDm[v * TCAP + e] = sDm[i][f];
        int m = pmask[p] & ((1 << i) - 1);
        int prev = -1;
        if (m) {
          int j = 31 - __clz(m);
          int cj = cnt[j];
          for (int f2 = 0; f2 < cj; f2++)
            if (sP[j][f2] == p) { prev = offs[j] + f2; break; }
        }
        entPrev[v * TCAP + e] = prev;
      }
    }
  }
  __syncthreads();
  for (int p = t; p < N; p += 256) {
    int m = pmask[p];
    if (m) {
      int u = atomicAdd(&sh_u, 1);
      int j = 31 - __clz(m);
      int li = -1;
      int cj = cnt[j];
      for (int f2 = 0; f2 < cj; f2++)
        if (sP[j][f2] == p) { li = offs[j] + f2; break; }
      lastPG[v * TCAP + u] = p;
      lastIG[v * TCAP + u] = li;
      lastMG[v * TCAP + u] = m;
      int mm = m;
      while (mm) {
        int bi = __ffs(mm) - 1; mm &= mm - 1;
        int m2 = m & ((1 << bi) - 1);
        while (m2) {
          int bj = __ffs(m2) - 1; m2 &= m2 - 1;
          atomicAdd(&cmat_sh[bi * 16 + bj], 1);
        }
      }
    }
  }
  __syncthreads();
  if (t == 0) cntG[v * 2 + 1] = sh_u;
  for (int x = t; x < 256; x += 256) cmatG[v * 256 + x] = cmat_sh[x];
  for (int x = t; x < 17; x += 256) offsG[v * 17 + x] = offs[x];
}

// ---------------------------------------------------------------------------
// k_step: ONE fused encoder iteration (gather-first reformulation).
//   msg[r] = sum_{e in in(r)} A_t[src_e]            (fp32, matches reference)
//   A_{t+1} = relu([A_t | msg] @ [W_self; W_nbr] + b)
// Grid: (128 row-groups x 2 col-halves) x 256 thr.  Block tile: 16 rows x
// 128 cols.  msg staged bf16-split in LDS; A-self + W streamed from L2-hot
// global; epilogue writes states fp32 + bf16 split of next A.  No Z buffer.
// ---------------------------------------------------------------------------
__global__ __launch_bounds__(256) void k_step(
    const ushort* __restrict__ Ah, const ushort* __restrict__ Al,
    const float* __restrict__ Acur,
    const ushort* __restrict__ W2h, const ushort* __restrict__ W2l,
    const float* __restrict__ bias,
    const int* __restrict__ row_ptr, const int* __restrict__ csr_src,
    float* __restrict__ stnext, ushort* __restrict__ NAh,
    ushort* __restrict__ NAl) {
  __shared__ __align__(16) ushort Mh[16][264], Ml[16][264];  // 16.5 KB
  const int tid = threadIdx.x, wave = tid >> 6, lane = tid & 63;
  const int quad = lane >> 4, l16 = lane & 15;
  const int r0 = blockIdx.x * 16, ch = blockIdx.y;
  const float4* Ap = (const float4*)Acur;

  // ---- gather phase: 4 rows per wave, 4 loads in flight ----
  for (int rr = wave; rr < 16; rr += 4) {
    int r = r0 + rr;
    int e0 = row_ptr[r], e1 = row_ptr[r + 1];
    float4 s0 = {0.f, 0.f, 0.f, 0.f}, s1 = s0, s2 = s0, s3 = s0;
    int e = e0;
    for (; e + 3 < e1; e += 4) {
      int i0 = csr_src[e], i1 = csr_src[e + 1];
      int i2 = csr_src[e + 2], i3 = csr_src[e + 3];
      float4 x0 = Ap[(size_t)i0 * 64 + lane];
      float4 x1 = Ap[(size_t)i1 * 64 + lane];
      float4 x2 = Ap[(size_t)i2 * 64 + lane];
      float4 x3 = Ap[(size_t)i3 * 64 + lane];
      s0.x += x0.x; s0.y += x0.y; s0.z += x0.z; s0.w += x0.w;
      s1.x += x1.x; s1.y += x1.y; s1.z += x1.z; s1.w += x1.w;
      s2.x += x2.x; s2.y += x2.y; s2.z += x2.z; s2.w += x2.w;
      s3.x += x3.x; s3.y += x3.y; s3.z += x3.z; s3.w += x3.w;
    }
    for (; e < e1; e++) {
      float4 x0 = Ap[(size_t)csr_src[e] * 64 + lane];
      s0.x += x0.x; s0.y += x0.y; s0.z += x0.z; s0.w += x0.w;
    }
    float m0 = s0.x + s1.x + s2.x + s3.x;
    float m1 = s0.y + s1.y + s2.y + s3.y;
    float m2 = s0.z + s1.z + s2.z + s3.z;
    float m3 = s0.w + s1.w + s2.w + s3.w;
    ushort h0 = bf16_rn(m0), h1 = bf16_rn(m1);
    ushort h2 = bf16_rn(m2), h3 = bf16_rn(m3);
    *(ushort4*)&Mh[rr][lane * 4] = make_ushort4(h0, h1, h2, h3);
    *(ushort4*)&Ml[rr][lane * 4] = make_ushort4(
        bf16_rn(m0 - bf16_f(h0)), bf16_rn(m1 - bf16_f(h1)),
        bf16_rn(m2 - bf16_f(h2)), bf16_rn(m3 - bf16_f(h3)));
  }
  __syncthreads();

  // ---- GEMM phase: K=512 (256 self from global, 256 msg from LDS) ----
  const int n0 = ch * 128 + wave * 32 + l16;
  const int n1 = n0 + 16;
  f32x4 acc0 = {0.f, 0.f, 0.f, 0.f}, acc1 = {0.f, 0.f, 0.f, 0.f};
#pragma unroll 4
  for (int ks = 0; ks < 8; ks++) {
    const int kk = ks * 32 + quad * 8;
    size_t aa = a_addr(r0 + l16, kk);
    bf16x8 a_h = *(const bf16x8*)&Ah[aa];
    bf16x8 a_l = *(const bf16x8*)&Al[aa];
    size_t w0 = wt_addr(n0, kk), w1 = wt_addr(n1, kk);
    bf16x8 w0h = *(const bf16x8*)&W2h[w0];
    bf16x8 w0l = *(const bf16x8*)&W2l[w0];
    bf16x8 w1h = *(const bf16x8*)&W2h[w1];
    bf16x8 w1l = *(const bf16x8*)&W2l[w1];
    acc0 = __builtin_amdgcn_mfma_f32_16x16x32_bf16(a_h, w0h, acc0, 0, 0, 0);
    acc0 = __builtin_amdgcn_mfma_f32_16x16x32_bf16(a_h, w0l, acc0, 0, 0, 0);
    acc0 = __builtin_amdgcn_mfma_f32_16x16x32_bf16(a_l, w0h, acc0, 0, 0, 0);
    acc1 = __builtin_amdgcn_mfma_f32_16x16x32_bf16(a_h, w1h, acc1, 0, 0, 0);
    acc1 = __builtin_amdgcn_mfma_f32_16x16x32_bf16(a_h, w1l, acc1, 0, 0, 0);
    acc1 = __builtin_amdgcn_mfma_f32_16x16x32_bf16(a_l, w1h, acc1, 0, 0, 0);
  }
#pragma unroll 4
  for (int ks = 0; ks < 8; ks++) {
    const int km = ks * 32 + quad * 8;       // msg-local k
    const int kk = 256 + km;                 // absolute k for W
    bf16x8 a_h = *(const bf16x8*)&Mh[l16][km];
    bf16x8 a_l = *(const bf16x8*)&Ml[l16][km];
    size_t w0 = wt_addr(n0, kk), w1 = wt_addr(n1, kk);
    bf16x8 w0h = *(const bf16x8*)&W2h[w0];
    bf16x8 w0l = *(const bf16x8*)&W2l[w0];
    bf16x8 w1h = *(const bf16x8*)&W2h[w1];
    bf16x8 w1l = *(const bf16x8*)&W2l[w1];
    acc0 = __builtin_amdgcn_mfma_f32_16x16x32_bf16(a_h, w0h, acc0, 0, 0, 0);
    acc0 = __builtin_amdgcn_mfma_f32_16x16x32_bf16(a_h, w0l, acc0, 0, 0, 0);
    acc0 = __builtin_amdgcn_mfma_f32_16x16x32_bf16(a_l, w0h, acc0, 0, 0, 0);
    acc1 = __builtin_amdgcn_mfma_f32_16x16x32_bf16(a_h, w1h, acc1, 0, 0, 0);
    acc1 = __builtin_amdgcn_mfma_f32_16x16x32_bf16(a_h, w1l, acc1, 0, 0, 0);
    acc1 = __builtin_amdgcn_mfma_f32_16x16x32_bf16(a_l, w1h, acc1, 0, 0, 0);
  }

  // ---- epilogue: relu+bias, write states fp32 + bf16 split ----
  const float b0 = bias[n0], b1 = bias[n1];
#pragma unroll
  for (int j = 0; j < 4; j++) {
    int row = r0 + quad * 4 + j;
    float v0 = fmaxf(acc0[j] + b0, 0.f);
    float v1 = fmaxf(acc1[j] + b1, 0.f);
    stnext[(size_t)row * D + n0] = v0;
    stnext[(size_t)row * D + n1] = v1;
    ushort h0 = bf16_rn(v0), h1 = bf16_rn(v1);
    size_t a0 = a_addr(row, n0), a1 = a_addr(row, n1);
    NAh[a0] = h0;
    NAh[a1] = h1;
    NAl[a0] = bf16_rn(v0 - bf16_f(h0));
    NAl[a1] = bf16_rn(v1 - bf16_f(h1));
  }
}

// ---------------------------------------------------------------------------
// k_pi: LINEAR reformulation, 256 threads/block (4 waves).  (verified R1)
// ---------------------------------------------------------------------------
#define PI_LDS_BYTES (TCAP * 64 * 4 + 16 * 64 * 4 + 16 * 64 * 4 + 256 * 4 + \
                      3 * TCAP * 4 + 17 * 4 + 16 * 4 + 256 * 4)
__global__ __launch_bounds__(256) void k_pi(
    const float* __restrict__ states, float* __restrict__ out,
    const int* __restrict__ variants,
    const int* __restrict__ entP, const int* __restrict__ entPrev,
    const int* __restrict__ entDm, const int* __restrict__ offsG,
    const int* __restrict__ kidxG, const int* __restrict__ tlG,
    const int* __restrict__ cmatG, const int* __restrict__ lastPG,
    const int* __restrict__ lastIG, const int* __restrict__ lastMG,
    const int* __restrict__ cntG) {
  extern __shared__ __align__(16) float smf[];
  float* catb = smf;                       // [TCAP][64]  (becomes pref)
  float* S_lds = catb + TCAP * 64;         // [16][64]
  float* aS = S_lds + 16 * 64;             // [16][64] per-step sums
  float* cmatf = aS + 16 * 64;             // [256]
  int* eP  = (int*)(cmatf + 256);          // [TCAP]
  int* ePr = eP + TCAP;
  int* eDm = ePr + TCAP;
  int* offs = eDm + TCAP;                  // [17]
  int* kidx = offs + 17;                   // [16]
  int* tl = kidx + 16;                     // [256]
  int v = blockIdx.x / 12, cgi = blockIdx.x % 12;
  int grp = cgi >> 2;
  int tid = threadIdx.x, lane = tid & 63, w = tid >> 6;
  int cl = (cgi & 3) * 64 + lane;          // 0..255 within third
  int col = cgi * 64 + lane;               // 0..767

  int T = cntG[v * 2 + 0], U = cntG[v * 2 + 1];
  for (int x = tid; x < T; x += 256) {
    eP[x] = entP[v * TCAP + x];
    ePr[x] = entPrev[v * TCAP + x];
    eDm[x] = entDm[v * TCAP + x];
  }
  for (int x = tid; x < 17; x += 256) offs[x] = offsG[v * 17 + x];
  if (tid < 16) kidx[tid] = kidxG[v * 16 + tid];
  for (int x = tid; x < 256; x += 256) {
    tl[x] = tlG[v * 256 + x];
    cmatf[x] = (float)cmatG[v * 256 + x];
  }
  __syncthreads();

  // cat fill: waves split the entries of each step
  for (int i = 0; i < L; i++) {
    int kk = kidx[i]; if (kk > NSTATE - 1) kk = NSTATE - 1;
    const float* embS = states + (size_t)kk * N * D;
    int o0 = offs[i], o1 = offs[i + 1];
    if (grp == 0) {
      for (int e = o0 + w; e < o1; e += 4)
        catb[e * 64 + lane] = embS[(size_t)eP[e] * D + cl];
    } else if (grp == 1) {
      float embA = embS[(size_t)variants[v * L + i] * D + cl];
      for (int e = o0 + w; e < o1; e += 4) catb[e * 64 + lane] = embA;
    } else {
      for (int e = o0 + w; e < o1; e += 4) {
        float sa = 0.f;
        int bm = eDm[e];
        while (bm) {
          int q = __ffs(bm) - 1; bm &= bm - 1;
          sa += embS[(size_t)tl[i * 16 + q] * D + cl];
        }
        catb[e * 64 + lane] = sa;
      }
    }
  }
  __syncthreads();
  // prefix over place-chains, chains distributed across waves
  for (int u = w; u < U; u += 4) {
    int li = lastIG[v * TCAP + u];
    int len = 0;
    for (int c2 = li; c2 >= 0; c2 = ePr[c2]) len++;
    for (int j = 1; j < len; j++) {        // root -> last order
      int c2 = li;
      for (int k = 0; k < len - 1 - j; k++) c2 = ePr[c2];
      catb[c2 * 64 + lane] += catb[ePr[c2] * 64 + lane];
    }
  }
  __syncthreads();
  // per-step sums of pref
  for (int i = w; i < 16; i += 4) {
    float a = 0.f;
    for (int e = offs[i]; e < offs[i + 1]; e++) a += catb[e * 64 + lane];
    aS[i * 64 + lane] = a;
  }
  __syncthreads();
  // S recurrence (serial over 16 steps, wave 0)
  if (w == 0) {
    float S[16];
    float Sp = 0.f;
#pragma unroll
    for (int i = 0; i < 16; i++) {
      float sv = Sp + aS[i * 64 + lane];
#pragma unroll
      for (int j = 0; j < 16; j++)
        if (j < i) sv += cmatf[i * 16 + j] * S[j];
      S[i] = sv;
      S_lds[i * 64 + lane] = sv;
      Sp = sv;
    }
  }
  __syncthreads();
  // outputs, places distributed across waves
  for (int u = w; u < U; u += 4) {
    int p = lastPG[v * TCAP + u];
    int li = lastIG[v * TCAP + u];
    int m = lastMG[v * TCAP + u];
    float acc = catb[li * 64 + lane];
    while (m) {
      int q = __ffs(m) - 1; m &= m - 1;
      acc += S_lds[q * 64 + lane];
    }
    atomicAdd(&out[(size_t)p * C + col], acc);
  }
}

// ---------------------------------------------------------------------------
extern "C" void kernel_launch(void* const* d_in, const int* in_sizes, int n_in,
                              void* d_out, int out_size, void* d_ws, size_t ws_size,
                              hipStream_t stream) {
  const float* emb      = (const float*)d_in[0];
  const float* Ws       = (const float*)d_in[1];
  const float* Wn       = (const float*)d_in[2];
  const float* bias     = (const float*)d_in[3];
  const int*   variants = (const int*)d_in[4];
  const int*   adj      = (const int*)d_in[5];
  const int*   ei       = (const int*)d_in[6];
  const int    E        = in_sizes[6] / 2;
  float* out            = (float*)d_out;

  char* base = (char*)d_ws;
  float* states = (float*)base;            base += (size_t)NSTATE * N * D * 4;
  ushort* W2h   = (ushort*)base;           base += (size_t)256 * 512 * 2;
  ushort* W2l   = (ushort*)base;           base += (size_t)256 * 512 * 2;
  ushort* A0h   = (ushort*)base;           base += (size_t)N * D * 2;
  ushort* A0l   = (ushort*)base;           base += (size_t)N * D * 2;
  ushort* A1h   = (ushort*)base;           base += (size_t)N * D * 2;
  ushort* A1l   = (ushort*)base;           base += (size_t)N * D * 2;
  int* row_ptr  = (int*)base;              base += (N + 1) * 4;
  int* fillpos  = (int*)base;              base += N * 4;
  int* csr_src  = (int*)base;              base += (size_t)E * 4;
  int* stepP    = (int*)base;              base += V * L * FCAP * 4;
  int* stepDm   = (int*)base;              base += V * L * FCAP * 4;
  int* stepCnt  = (int*)base;              base += V * L * 4;
  int* hasG     = (int*)base;              base += V * L * 4;
  int* entP     = (int*)base;              base += V * TCAP * 4;
  int* entPrev  = (int*)base;              base += V * TCAP * 4;
  int* entDm    = (int*)base;              base += V * TCAP * 4;
  int* offsG    = (int*)base;              base += V * 17 * 4;
  int* kidxG    = (int*)base;              base += V * 16 * 4;
  int* tlG      = (int*)base;              base += V * 256 * 4;
  int* cmatG    = (int*)base;              base += V * 256 * 4;
  int* lastPG   = (int*)base;              base += V * TCAP * 4;
  int* lastIG   = (int*)base;              base += V * TCAP * 4;
  int* lastMG   = (int*)base;              base += V * TCAP * 4;
  int* cntG     = (int*)base;              base += V * 2 * 4;

  hipFuncSetAttribute((const void*)k_pi,
                      hipFuncAttributeMaxDynamicSharedMemorySize, PI_LDS_BYTES);

  k_init<<<512, 256, 0, stream>>>(emb, Ws, Wn, states, W2h, W2l, A0h, A0l,
                                  out, fillpos);
  k_degA<<<128 + V * L, 256, 0, stream>>>(ei, E, fillpos, adj, variants,
                                          stepP, stepDm, stepCnt, hasG, tlG);
  k_scan<<<1, 256, 0, stream>>>(fillpos, row_ptr);
  k_fillB<<<128 + V, 256, 0, stream>>>(ei, E, fillpos, csr_src, stepP, stepDm,
                                       stepCnt, hasG, entP, entPrev, entDm,
                                       offsG, kidxG, cmatG, lastPG, lastIG,
                                       lastMG, cntG);

  ushort* AH[2] = {A0h, A1h};
  ushort* AL[2] = {A0l, A1l};
  for (int s = 0; s < NAPP; s++) {
    int cur = s & 1, nxt = cur ^ 1;
    k_step<<<dim3(128, 2), 256, 0, stream>>>(
        AH[cur], AL[cur], states + (size_t)s * N * D, W2h, W2l, bias,
        row_ptr, csr_src, states + (size_t)(s + 1) * N * D, AH[nxt], AL[nxt]);
  }
  k_pi<<<V * 12, 256, PI_LDS_BYTES, stream>>>(states, out, variants, entP,
                                              entPrev, entDm, offsG, kidxG, tlG,
                                              cmatG, lastPG, lastIG, lastMG,
                                              cntG);
}

// Round 3
// 431.878 us; speedup vs baseline: 3.8232x; 1.1218x over previous
//
#include <hip/hip_runtime.h>

// Problem constants (fixed by the reference)
#define N 2048
#define D 256
#define C 768          // 3*D
#define V 2
#define L 16
#define NSTATE 15      // S_0..S_14 (step-15 mask provably empty)
#define NAPP 14        // encoder applications
#define TCAP 256       // canonical masked-entry cap per variant (expected ~107)
#define FCAP 64        // follower cap per step (expected ~32)

typedef __attribute__((ext_vector_type(8))) short bf16x8;
typedef __attribute__((ext_vector_type(4))) float f32x4;

__device__ __forceinline__ ushort bf16_rn(float x) {
  unsigned u = __float_as_uint(x);
  u += 0x7FFFu + ((u >> 16) & 1u);
  return (ushort)(u >> 16);
}
__device__ __forceinline__ float bf16_f(ushort h) {
  return __uint_as_float(((unsigned)h) << 16);
}

// A chunk-tiled layout (chunk = 32 rows x 64 k = 2048 ushorts = 4 KB); k<256.
__device__ __forceinline__ size_t a_addr(int row, int k) {
  return ((size_t)(row >> 5) * 4 + (k >> 6)) * 2048 + (row & 31) * 64 + (k & 63);
}
// W2 layout: [n=256 output cols][k=512 input dims], chunked 32n x 64k.
__device__ __forceinline__ size_t wt_addr(int n, int k) {
  return ((size_t)(n >> 5) * 8 + (k >> 6)) * 2048 + (n & 31) * 64 + (k & 63);
}

// ---------------------------------------------------------------------------
// k_init: states0 = emb; A0 bf16 split (chunked); W2=[W_self;W_nbr] as
// [n][k=512] bf16 split (chunked); zero out / fillpos.
// ---------------------------------------------------------------------------
__global__ __launch_bounds__(256) void k_init(
    const float* __restrict__ emb, const float* __restrict__ Ws,
    const float* __restrict__ Wn, float* __restrict__ states0,
    ushort* __restrict__ W2h, ushort* __restrict__ W2l,
    ushort* __restrict__ A0hi, ushort* __restrict__ A0lo,
    float* __restrict__ out, int* __restrict__ fillpos) {
  size_t i = (size_t)blockIdx.x * 256 + threadIdx.x;
  size_t stride = (size_t)gridDim.x * 256;
  for (size_t x = i; x < (size_t)N * D; x += stride) {
    float v = emb[x];
    states0[x] = v;
    ushort h = bf16_rn(v);
    ushort l = bf16_rn(v - bf16_f(h));
    size_t a = a_addr((int)(x >> 8), (int)(x & 255));
    A0hi[a] = h;
    A0lo[a] = l;
  }
  for (size_t x = i; x < (size_t)256 * 512; x += stride) {
    int n = (int)(x >> 9), k = (int)(x & 511);
    float v = (k < 256) ? Ws[(size_t)k * 256 + n]
                        : Wn[(size_t)(k - 256) * 256 + n];
    ushort h = bf16_rn(v);
    size_t a = wt_addr(n, k);
    W2h[a] = h;
    W2l[a] = bf16_rn(v - bf16_f(h));
  }
  for (size_t x = i; x < (size_t)N * C; x += stride) out[x] = 0.f;
  for (size_t x = i; x < N; x += stride) fillpos[x] = 0;
}

// ---------------------------------------------------------------------------
// k_degA: fused k_deg (blocks 0..127) + k_metaA (blocks 128..159).
// ---------------------------------------------------------------------------
__global__ __launch_bounds__(256) void k_degA(
    const int* __restrict__ ei, int E, int* __restrict__ fillpos,
    const int* __restrict__ adj, const int* __restrict__ variants,
    int* __restrict__ stepP, int* __restrict__ stepDm,
    int* __restrict__ stepCnt, int* __restrict__ hasG, int* __restrict__ tlG) {
  __shared__ int tl_sh[16];
  __shared__ int foll[FCAP], fbits[FCAP];
  __shared__ int sh_tc, sh_fcnt, sh_ecnt;
  int t = threadIdx.x;
  if (blockIdx.x < 128) {
    for (int e = blockIdx.x * 256 + t; e < E; e += 128 * 256)
      atomicAdd(&fillpos[ei[E + e]], 1);
    return;
  }
  int vi = blockIdx.x - 128;
  int v = vi / L, i = vi % L;
  int a = variants[vi];
  if (t == 0) {
    int cnt = 0;
    for (int j = i + 1; j < L; j++) {
      int x = variants[v * L + j];
      bool dup = false;
      for (int q = 0; q < cnt; q++) if (tl_sh[q] == x) dup = true;
      if (!dup) tl_sh[cnt++] = x;
    }
    sh_tc = cnt;
    sh_fcnt = 0;
    sh_ecnt = 0;
    for (int q = 0; q < cnt; q++) tlG[vi * 16 + q] = tl_sh[q];
  }
  __syncthreads();
  for (int p = t; p < N; p += 256) {
    if (adj[(size_t)a * N + p] != 0) {
      int f = atomicAdd(&sh_fcnt, 1);
      if (f < FCAP) foll[f] = p;
    }
  }
  __syncthreads();
  int fc = sh_fcnt < FCAP ? sh_fcnt : FCAP;
  int tc = sh_tc;
  for (int x = t; x < fc; x += 256) fbits[x] = 0;
  __syncthreads();
  for (int x = t; x < fc * tc; x += 256) {
    int fi = x / tc, q = x - fi * tc;
    if (adj[(size_t)foll[fi] * N + tl_sh[q]] != 0) atomicOr(&fbits[fi], 1 << q);
  }
  __syncthreads();
  for (int fi = t; fi < fc; fi += 256) {
    int bits = fbits[fi];
    if (bits) {
      int e = atomicAdd(&sh_ecnt, 1);
      stepP[vi * FCAP + e] = foll[fi];
      stepDm[vi * FCAP + e] = bits;
    }
  }
  __syncthreads();
  if (t == 0) {
    stepCnt[vi] = sh_ecnt;
    hasG[vi] = (sh_fcnt > 0);
  }
}

// ---------------------------------------------------------------------------
// k_scan: exclusive prefix over degrees -> row_ptr; resets fillpos to starts.
// ---------------------------------------------------------------------------
__global__ __launch_bounds__(256) void k_scan(int* __restrict__ fillpos,
                                              int* __restrict__ row_ptr) {
  __shared__ int part[256];
  __shared__ int base[257];
  int t = threadIdx.x;
  int v[8];
  int s = 0;
  for (int j = 0; j < 8; j++) { v[j] = fillpos[t * 8 + j]; s += v[j]; }
  part[t] = s;
  __syncthreads();
  if (t == 0) {
    int acc = 0;
    for (int q = 0; q < 256; q++) { base[q] = acc; acc += part[q]; }
    base[256] = acc;
  }
  __syncthreads();
  int acc = base[t];
  for (int j = 0; j < 8; j++) {
    row_ptr[t * 8 + j] = acc;
    fillpos[t * 8 + j] = acc;
    acc += v[j];
  }
  if (t == 255) row_ptr[N] = base[256];
}

// ---------------------------------------------------------------------------
// k_fillB: fused k_fill (blocks 0..127) + k_metaB (blocks 128..128+V-1).
// ---------------------------------------------------------------------------
__global__ __launch_bounds__(256) void k_fillB(
    const int* __restrict__ ei, int E, int* __restrict__ fillpos,
    int* __restrict__ csr_src,
    const int* __restrict__ stepP, const int* __restrict__ stepDm,
    const int* __restrict__ stepCnt, const int* __restrict__ hasG,
    int* __restrict__ entP, int* __restrict__ entPrev, int* __restrict__ entDm,
    int* __restrict__ offsG, int* __restrict__ kidxG, int* __restrict__ cmatG,
    int* __restrict__ lastPG, int* __restrict__ lastIG, int* __restrict__ lastMG,
    int* __restrict__ cntG) {
  __shared__ int pmask[N];           // 8 KB
  __shared__ int sP[16][FCAP];       // 4 KB
  __shared__ int sDm[16][FCAP];      // 4 KB
  __shared__ int cnt[16], offs[17];
  __shared__ int cmat_sh[256];       // 1 KB
  __shared__ int sh_u;
  int t = threadIdx.x;
  if (blockIdx.x < 128) {
    for (int e = blockIdx.x * 256 + t; e < E; e += 128 * 256) {
      int dst = ei[E + e];
      int pos = atomicAdd(&fillpos[dst], 1);
      csr_src[pos] = ei[e];
    }
    return;
  }
  int v = blockIdx.x - 128;
  for (int p = t; p < N; p += 256) pmask[p] = 0;
  for (int x = t; x < 256; x += 256) cmat_sh[x] = 0;
  if (t < 16) cnt[t] = stepCnt[v * L + t];
  if (t == 0) sh_u = 0;
  __syncthreads();
  if (t == 0) {
    int acc = 0;
    for (int i = 0; i < 16; i++) {
      offs[i] = acc < TCAP ? acc : TCAP;
      acc += cnt[i];
    }
    offs[16] = acc < TCAP ? acc : TCAP;
    cntG[v * 2 + 0] = offs[16];
    int k = 0;
    for (int i = 0; i < L; i++) {
      kidxG[v * 16 + i] = k;
      if (hasG[v * L + i]) k++;
    }
  }
  for (int x = t; x < 16 * FCAP; x += 256) {
    int i = x >> 6, f = x & 63;
    if (f < stepCnt[v * L + i]) {
      int p = stepP[(v * L + i) * FCAP + f];
      sP[i][f] = p;
      sDm[i][f] = stepDm[(v * L + i) * FCAP + f];
      atomicOr(&pmask[p], 1 << i);
    }
  }
  __syncthreads();
  for (int x = t; x < 16 * FCAP; x += 256) {
    int i = x >> 6, f = x & 63;
    if (f < cnt[i]) {
      int e = offs[i] + f;
      if (e < TCAP) {
        int p = sP[i][f];
        entP[v * TCAP + e] = p;
        entDm[v * TCAP + e] = sDm[i][f];
        int m = pmask[p] & ((1 << i) - 1);
        int prev = -1;
        if (m) {
          int j = 31 - __clz(m);
          int cj = cnt[j];
          for (int f2 = 0; f2 < cj; f2++)
            if (sP[j][f2] == p) { prev = offs[j] + f2; break; }
        }
        entPrev[v * TCAP + e] = prev;
      }
    }
  }
  __syncthreads();
  for (int p = t; p < N; p += 256) {
    int m = pmask[p];
    if (m) {
      int u = atomicAdd(&sh_u, 1);
      int j = 31 - __clz(m);
      int li = -1;
      int cj = cnt[j];
      for (int f2 = 0; f2 < cj; f2++)
        if (sP[j][f2] == p) { li = offs[j] + f2; break; }
      lastPG[v * TCAP + u] = p;
      lastIG[v * TCAP + u] = li;
      lastMG[v * TCAP + u] = m;
      int mm = m;
      while (mm) {
        int bi = __ffs(mm) - 1; mm &= mm - 1;
        int m2 = m & ((1 << bi) - 1);
        while (m2) {
          int bj = __ffs(m2) - 1; m2 &= m2 - 1;
          atomicAdd(&cmat_sh[bi * 16 + bj], 1);
        }
      }
    }
  }
  __syncthreads();
  if (t == 0) cntG[v * 2 + 1] = sh_u;
  for (int x = t; x < 256; x += 256) cmatG[v * 256 + x] = cmat_sh[x];
  for (int x = t; x < 17; x += 256) offsG[v * 17 + x] = offs[x];
}

// ---------------------------------------------------------------------------
// k_step: ONE fused encoder iteration (gather-first reformulation).
//   msg[r] = sum_{e in in(r)} A_t[src_e]            (fp32, matches reference)
//   A_{t+1} = relu([A_t | msg] @ [W_self; W_nbr] + b)
// Grid (128,2) x 512 thr (8 waves) -> 256 blocks = 1 block/CU = 2 waves/SIMD
// (R2 post-mortem: 256-thr version was 1 wave/SIMD -> latency-exposed).
// Block tile: 16 rows x 128 cols; wave tile 16x16 (single acc).
// ---------------------------------------------------------------------------
__global__ __launch_bounds__(512) void k_step(
    const ushort* __restrict__ Ah, const ushort* __restrict__ Al,
    const float* __restrict__ Acur,
    const ushort* __restrict__ W2h, const ushort* __restrict__ W2l,
    const float* __restrict__ bias,
    const int* __restrict__ row_ptr, const int* __restrict__ csr_src,
    float* __restrict__ stnext, ushort* __restrict__ NAh,
    ushort* __restrict__ NAl) {
  __shared__ __align__(16) ushort Mh[16][264], Ml[16][264];  // 16.5 KB
  const int tid = threadIdx.x, wave = tid >> 6, lane = tid & 63;
  const int quad = lane >> 4, l16 = lane & 15;
  const int r0 = blockIdx.x * 16, ch = blockIdx.y;
  const float4* Ap = (const float4*)Acur;

  // ---- gather phase: 2 rows per wave, 4 loads in flight ----
  for (int rr = wave; rr < 16; rr += 8) {
    int r = r0 + rr;
    int e0 = row_ptr[r], e1 = row_ptr[r + 1];
    float4 s0 = {0.f, 0.f, 0.f, 0.f}, s1 = s0, s2 = s0, s3 = s0;
    int e = e0;
    for (; e + 3 < e1; e += 4) {
      int i0 = csr_src[e], i1 = csr_src[e + 1];
      int i2 = csr_src[e + 2], i3 = csr_src[e + 3];
      float4 x0 = Ap[(size_t)i0 * 64 + lane];
      float4 x1 = Ap[(size_t)i1 * 64 + lane];
      float4 x2 = Ap[(size_t)i2 * 64 + lane];
      float4 x3 = Ap[(size_t)i3 * 64 + lane];
      s0.x += x0.x; s0.y += x0.y; s0.z += x0.z; s0.w += x0.w;
      s1.x += x1.x; s1.y += x1.y; s1.z += x1.z; s1.w += x1.w;
      s2.x += x2.x; s2.y += x2.y; s2.z += x2.z; s2.w += x2.w;
      s3.x += x3.x; s3.y += x3.y; s3.z += x3.z; s3.w += x3.w;
    }
    for (; e < e1; e++) {
      float4 x0 = Ap[(size_t)csr_src[e] * 64 + lane];
      s0.x += x0.x; s0.y += x0.y; s0.z += x0.z; s0.w += x0.w;
    }
    float m0 = s0.x + s1.x + s2.x + s3.x;
    float m1 = s0.y + s1.y + s2.y + s3.y;
    float m2 = s0.z + s1.z + s2.z + s3.z;
    float m3 = s0.w + s1.w + s2.w + s3.w;
    ushort h0 = bf16_rn(m0), h1 = bf16_rn(m1);
    ushort h2 = bf16_rn(m2), h3 = bf16_rn(m3);
    *(ushort4*)&Mh[rr][lane * 4] = make_ushort4(h0, h1, h2, h3);
    *(ushort4*)&Ml[rr][lane * 4] = make_ushort4(
        bf16_rn(m0 - bf16_f(h0)), bf16_rn(m1 - bf16_f(h1)),
        bf16_rn(m2 - bf16_f(h2)), bf16_rn(m3 - bf16_f(h3)));
  }
  __syncthreads();

  // ---- GEMM phase: K=512 (256 self from global, 256 msg from LDS) ----
  const int n0 = ch * 128 + wave * 16 + l16;
  f32x4 acc0 = {0.f, 0.f, 0.f, 0.f};
#pragma unroll 4
  for (int ks = 0; ks < 8; ks++) {
    const int kk = ks * 32 + quad * 8;
    size_t aa = a_addr(r0 + l16, kk);
    bf16x8 a_h = *(const bf16x8*)&Ah[aa];
    bf16x8 a_l = *(const bf16x8*)&Al[aa];
    size_t w0 = wt_addr(n0, kk);
    bf16x8 w0h = *(const bf16x8*)&W2h[w0];
    bf16x8 w0l = *(const bf16x8*)&W2l[w0];
    acc0 = __builtin_amdgcn_mfma_f32_16x16x32_bf16(a_h, w0h, acc0, 0, 0, 0);
    acc0 = __builtin_amdgcn_mfma_f32_16x16x32_bf16(a_h, w0l, acc0, 0, 0, 0);
    acc0 = __builtin_amdgcn_mfma_f32_16x16x32_bf16(a_l, w0h, acc0, 0, 0, 0);
  }
#pragma unroll 4
  for (int ks = 0; ks < 8; ks++) {
    const int km = ks * 32 + quad * 8;       // msg-local k
    const int kk = 256 + km;                 // absolute k for W
    bf16x8 a_h = *(const bf16x8*)&Mh[l16][km];
    bf16x8 a_l = *(const bf16x8*)&Ml[l16][km];
    size_t w0 = wt_addr(n0, kk);
    bf16x8 w0h = *(const bf16x8*)&W2h[w0];
    bf16x8 w0l = *(const bf16x8*)&W2l[w0];
    acc0 = __builtin_amdgcn_mfma_f32_16x16x32_bf16(a_h, w0h, acc0, 0, 0, 0);
    acc0 = __builtin_amdgcn_mfma_f32_16x16x32_bf16(a_h, w0l, acc0, 0, 0, 0);
    acc0 = __builtin_amdgcn_mfma_f32_16x16x32_bf16(a_l, w0h, acc0, 0, 0, 0);
  }

  // ---- epilogue: relu+bias, write states fp32 + bf16 split ----
  const float b0 = bias[n0];
#pragma unroll
  for (int j = 0; j < 4; j++) {
    int row = r0 + quad * 4 + j;
    float v0 = fmaxf(acc0[j] + b0, 0.f);
    stnext[(size_t)row * D + n0] = v0;
    ushort h0 = bf16_rn(v0);
    size_t a0 = a_addr(row, n0);
    NAh[a0] = h0;
    NAl[a0] = bf16_rn(v0 - bf16_f(h0));
  }
}

// ---------------------------------------------------------------------------
// k_pi: LINEAR reformulation, 256 threads/block (4 waves).  (verified R1)
// ---------------------------------------------------------------------------
#define PI_LDS_BYTES (TCAP * 64 * 4 + 16 * 64 * 4 + 16 * 64 * 4 + 256 * 4 + \
                      3 * TCAP * 4 + 17 * 4 + 16 * 4 + 256 * 4)
__global__ __launch_bounds__(256) void k_pi(
    const float* __restrict__ states, float* __restrict__ out,
    const int* __restrict__ variants,
    const int* __restrict__ entP, const int* __restrict__ entPrev,
    const int* __restrict__ entDm, const int* __restrict__ offsG,
    const int* __restrict__ kidxG, const int* __restrict__ tlG,
    const int* __restrict__ cmatG, const int* __restrict__ lastPG,
    const int* __restrict__ lastIG, const int* __restrict__ lastMG,
    const int* __restrict__ cntG) {
  extern __shared__ __align__(16) float smf[];
  float* catb = smf;                       // [TCAP][64]  (becomes pref)
  float* S_lds = catb + TCAP * 64;         // [16][64]
  float* aS = S_lds + 16 * 64;             // [16][64] per-step sums
  float* cmatf = aS + 16 * 64;             // [256]
  int* eP  = (int*)(cmatf + 256);          // [TCAP]
  int* ePr = eP + TCAP;
  int* eDm = ePr + TCAP;
  int* offs = eDm + TCAP;                  // [17]
  int* kidx = offs + 17;                   // [16]
  int* tl = kidx + 16;                     // [256]
  int v = blockIdx.x / 12, cgi = blockIdx.x % 12;
  int grp = cgi >> 2;
  int tid = threadIdx.x, lane = tid & 63, w = tid >> 6;
  int cl = (cgi & 3) * 64 + lane;          // 0..255 within third
  int col = cgi * 64 + lane;               // 0..767

  int T = cntG[v * 2 + 0], U = cntG[v * 2 + 1];
  for (int x = tid; x < T; x += 256) {
    eP[x] = entP[v * TCAP + x];
    ePr[x] = entPrev[v * TCAP + x];
    eDm[x] = entDm[v * TCAP + x];
  }
  for (int x = tid; x < 17; x += 256) offs[x] = offsG[v * 17 + x];
  if (tid < 16) kidx[tid] = kidxG[v * 16 + tid];
  for (int x = tid; x < 256; x += 256) {
    tl[x] = tlG[v * 256 + x];
    cmatf[x] = (float)cmatG[v * 256 + x];
  }
  __syncthreads();

  // cat fill: waves split the entries of each step
  for (int i = 0; i < L; i++) {
    int kk = kidx[i]; if (kk > NSTATE - 1) kk = NSTATE - 1;
    const float* embS = states + (size_t)kk * N * D;
    int o0 = offs[i], o1 = offs[i + 1];
    if (grp == 0) {
      for (int e = o0 + w; e < o1; e += 4)
        catb[e * 64 + lane] = embS[(size_t)eP[e] * D + cl];
    } else if (grp == 1) {
      float embA = embS[(size_t)variants[v * L + i] * D + cl];
      for (int e = o0 + w; e < o1; e += 4) catb[e * 64 + lane] = embA;
    } else {
      for (int e = o0 + w; e < o1; e += 4) {
        float sa = 0.f;
        int bm = eDm[e];
        while (bm) {
          int q = __ffs(bm) - 1; bm &= bm - 1;
          sa += embS[(size_t)tl[i * 16 + q] * D + cl];
        }
        catb[e * 64 + lane] = sa;
      }
    }
  }
  __syncthreads();
  // prefix over place-chains, chains distributed across waves
  for (int u = w; u < U; u += 4) {
    int li = lastIG[v * TCAP + u];
    int len = 0;
    for (int c2 = li; c2 >= 0; c2 = ePr[c2]) len++;
    for (int j = 1; j < len; j++) {        // root -> last order
      int c2 = li;
      for (int k = 0; k < len - 1 - j; k++) c2 = ePr[c2];
      catb[c2 * 64 + lane] += catb[ePr[c2] * 64 + lane];
    }
  }
  __syncthreads();
  // per-step sums of pref
  for (int i = w; i < 16; i += 4) {
    float a = 0.f;
    for (int e = offs[i]; e < offs[i + 1]; e++) a += catb[e * 64 + lane];
    aS[i * 64 + lane] = a;
  }
  __syncthreads();
  // S recurrence (serial over 16 steps, wave 0)
  if (w == 0) {
    float S[16];
    float Sp = 0.f;
#pragma unroll
    for (int i = 0; i < 16; i++) {
      float sv = Sp + aS[i * 64 + lane];
#pragma unroll
      for (int j = 0; j < 16; j++)
        if (j < i) sv += cmatf[i * 16 + j] * S[j];
      S[i] = sv;
      S_lds[i * 64 + lane] = sv;
      Sp = sv;
    }
  }
  __syncthreads();
  // outputs, places distributed across waves
  for (int u = w; u < U; u += 4) {
    int p = lastPG[v * TCAP + u];
    int li = lastIG[v * TCAP + u];
    int m = lastMG[v * TCAP + u];
    float acc = catb[li * 64 + lane];
    while (m) {
      int q = __ffs(m) - 1; m &= m - 1;
      acc += S_lds[q * 64 + lane];
    }
    atomicAdd(&out[(size_t)p * C + col], acc);
  }
}

// ---------------------------------------------------------------------------
extern "C" void kernel_launch(void* const* d_in, const int* in_sizes, int n_in,
                              void* d_out, int out_size, void* d_ws, size_t ws_size,
                              hipStream_t stream) {
  const float* emb      = (const float*)d_in[0];
  const float* Ws       = (const float*)d_in[1];
  const float* Wn       = (const float*)d_in[2];
  const float* bias     = (const float*)d_in[3];
  const int*   variants = (const int*)d_in[4];
  const int*   adj      = (const int*)d_in[5];
  const int*   ei       = (const int*)d_in[6];
  const int    E        = in_sizes[6] / 2;
  float* out            = (float*)d_out;

  char* base = (char*)d_ws;
  float* states = (float*)base;            base += (size_t)NSTATE * N * D * 4;
  ushort* W2h   = (ushort*)base;           base += (size_t)256 * 512 * 2;
  ushort* W2l   = (ushort*)base;           base += (size_t)256 * 512 * 2;
  ushort* A0h   = (ushort*)base;           base += (size_t)N * D * 2;
  ushort* A0l   = (ushort*)base;           base += (size_t)N * D * 2;
  ushort* A1h   = (ushort*)base;           base += (size_t)N * D * 2;
  ushort* A1l   = (ushort*)base;           base += (size_t)N * D * 2;
  int* row_ptr  = (int*)base;              base += (N + 1) * 4;
  int* fillpos  = (int*)base;              base += N * 4;
  int* csr_src  = (int*)base;              base += (size_t)E * 4;
  int* stepP    = (int*)base;              base += V * L * FCAP * 4;
  int* stepDm   = (int*)base;              base += V * L * FCAP * 4;
  int* stepCnt  = (int*)base;              base += V * L * 4;
  int* hasG     = (int*)base;              base += V * L * 4;
  int* entP     = (int*)base;              base += V * TCAP * 4;
  int* entPrev  = (int*)base;              base += V * TCAP * 4;
  int* entDm    = (int*)base;              base += V * TCAP * 4;
  int* offsG    = (int*)base;              base += V * 17 * 4;
  int* kidxG    = (int*)base;              base += V * 16 * 4;
  int* tlG      = (int*)base;              base += V * 256 * 4;
  int* cmatG    = (int*)base;              base += V * 256 * 4;
  int* lastPG   = (int*)base;              base += V * TCAP * 4;
  int* lastIG   = (int*)base;              base += V * TCAP * 4;
  int* lastMG   = (int*)base;              base += V * TCAP * 4;
  int* cntG     = (int*)base;              base += V * 2 * 4;

  hipFuncSetAttribute((const void*)k_pi,
                      hipFuncAttributeMaxDynamicSharedMemorySize, PI_LDS_BYTES);

  k_init<<<512, 256, 0, stream>>>(emb, Ws, Wn, states, W2h, W2l, A0h, A0l,
                                  out, fillpos);
  k_degA<<<128 + V * L, 256, 0, stream>>>(ei, E, fillpos, adj, variants,
                                          stepP, stepDm, stepCnt, hasG, tlG);
  k_scan<<<1, 256, 0, stream>>>(fillpos, row_ptr);
  k_fillB<<<128 + V, 256, 0, stream>>>(ei, E, fillpos, csr_src, stepP, stepDm,
                                       stepCnt, hasG, entP, entPrev, entDm,
                                       offsG, kidxG, cmatG, lastPG, lastIG,
                                       lastMG, cntG);

  ushort* AH[2] = {A0h, A1h};
  ushort* AL[2] = {A0l, A1l};
  for (int s = 0; s < NAPP; s++) {
    int cur = s & 1, nxt = cur ^ 1;
    k_step<<<dim3(128, 2), 512, 0, stream>>>(
        AH[cur], AL[cur], states + (size_t)s * N * D, W2h, W2l, bias,
        row_ptr, csr_src, states + (size_t)(s + 1) * N * D, AH[nxt], AL[nxt]);
  }
  k_pi<<<V * 12, 256, PI_LDS_BYTES, stream>>>(states, out, variants, entP,
                                              entPrev, entDm, offsG, kidxG, tlG,
                                              cmatG, lastPG, lastIG, lastMG,
                                              cntG);
}

// Round 4
// 346.194 us; speedup vs baseline: 4.7695x; 1.2475x over previous
//
#include <hip/hip_runtime.h>

// Problem constants (fixed by the reference)
#define N 2048
#define D 256
#define C 768          // 3*D
#define V 2
#define L 16
#define NSTATE 15      // S_0..S_14 (step-15 mask provably empty)
#define NAPP 14        // encoder applications
#define TCAP 256       // canonical masked-entry cap per variant (expected ~107)
#define FCAP 64        // follower cap per step (expected ~32)

typedef __attribute__((ext_vector_type(8))) short bf16x8;
typedef __attribute__((ext_vector_type(4))) float f32x4;

__device__ __forceinline__ ushort bf16_rn(float x) {
  unsigned u = __float_as_uint(x);
  u += 0x7FFFu + ((u >> 16) & 1u);
  return (ushort)(u >> 16);
}
__device__ __forceinline__ float bf16_f(ushort h) {
  return __uint_as_float(((unsigned)h) << 16);
}

// Chunk-tiled operand layouts (chunk = 32 rows x 64 k = 2048 ushorts = 4 KB).
__device__ __forceinline__ size_t a_addr(int row, int k) {
  return ((size_t)(row >> 5) * 4 + (k >> 6)) * 2048 + (row & 31) * 64 + (k & 63);
}
__device__ __forceinline__ size_t wt_addr(int n, int k) {
  return ((size_t)(n >> 5) * 4 + (k >> 6)) * 2048 + (n & 31) * 64 + (k & 63);
}

// ---------------------------------------------------------------------------
// k_init: states0 = emb; A0 bf16 split (chunked); Wt=[W_self|W_nbr]^T split
// (chunked); zero out / fillpos.
// ---------------------------------------------------------------------------
__global__ __launch_bounds__(256) void k_init(
    const float* __restrict__ emb, const float* __restrict__ Ws,
    const float* __restrict__ Wn, float* __restrict__ states0,
    ushort* __restrict__ WtHi, ushort* __restrict__ WtLo,
    ushort* __restrict__ A0hi, ushort* __restrict__ A0lo,
    float* __restrict__ out, int* __restrict__ fillpos) {
  size_t i = (size_t)blockIdx.x * 256 + threadIdx.x;
  size_t stride = (size_t)gridDim.x * 256;
  for (size_t x = i; x < (size_t)N * D; x += stride) {
    float v = emb[x];
    states0[x] = v;
    ushort h = bf16_rn(v);
    ushort l = bf16_rn(v - bf16_f(h));
    size_t a = a_addr((int)(x >> 8), (int)(x & 255));
    A0hi[a] = h;
    A0lo[a] = l;
  }
  for (size_t x = i; x < (size_t)512 * 256; x += stride) {
    int n = (int)(x >> 8), k = (int)(x & 255);
    float v = (n < 256) ? Ws[(size_t)k * 256 + n] : Wn[(size_t)k * 256 + (n - 256)];
    ushort h = bf16_rn(v);
    size_t a = wt_addr(n, k);
    WtHi[a] = h;
    WtLo[a] = bf16_rn(v - bf16_f(h));
  }
  for (size_t x = i; x < (size_t)N * C; x += stride) out[x] = 0.f;
  for (size_t x = i; x < N; x += stride) fillpos[x] = 0;
}

// ---------------------------------------------------------------------------
// k_degA: fused k_deg (blocks 0..127) + k_metaA (blocks 128..159).
// ---------------------------------------------------------------------------
__global__ __launch_bounds__(256) void k_degA(
    const int* __restrict__ ei, int E, int* __restrict__ fillpos,
    const int* __restrict__ adj, const int* __restrict__ variants,
    int* __restrict__ stepP, int* __restrict__ stepDm,
    int* __restrict__ stepCnt, int* __restrict__ hasG, int* __restrict__ tlG) {
  __shared__ int tl_sh[16];
  __shared__ int foll[FCAP], fbits[FCAP];
  __shared__ int sh_tc, sh_fcnt, sh_ecnt;
  int t = threadIdx.x;
  if (blockIdx.x < 128) {
    for (int e = blockIdx.x * 256 + t; e < E; e += 128 * 256)
      atomicAdd(&fillpos[ei[E + e]], 1);
    return;
  }
  int vi = blockIdx.x - 128;
  int v = vi / L, i = vi % L;
  int a = variants[vi];
  if (t == 0) {
    int cnt = 0;
    for (int j = i + 1; j < L; j++) {
      int x = variants[v * L + j];
      bool dup = false;
      for (int q = 0; q < cnt; q++) if (tl_sh[q] == x) dup = true;
      if (!dup) tl_sh[cnt++] = x;
    }
    sh_tc = cnt;
    sh_fcnt = 0;
    sh_ecnt = 0;
    for (int q = 0; q < cnt; q++) tlG[vi * 16 + q] = tl_sh[q];
  }
  __syncthreads();
  for (int p = t; p < N; p += 256) {
    if (adj[(size_t)a * N + p] != 0) {
      int f = atomicAdd(&sh_fcnt, 1);
      if (f < FCAP) foll[f] = p;
    }
  }
  __syncthreads();
  int fc = sh_fcnt < FCAP ? sh_fcnt : FCAP;
  int tc = sh_tc;
  for (int x = t; x < fc; x += 256) fbits[x] = 0;
  __syncthreads();
  for (int x = t; x < fc * tc; x += 256) {
    int fi = x / tc, q = x - fi * tc;
    if (adj[(size_t)foll[fi] * N + tl_sh[q]] != 0) atomicOr(&fbits[fi], 1 << q);
  }
  __syncthreads();
  for (int fi = t; fi < fc; fi += 256) {
    int bits = fbits[fi];
    if (bits) {
      int e = atomicAdd(&sh_ecnt, 1);
      stepP[vi * FCAP + e] = foll[fi];
      stepDm[vi * FCAP + e] = bits;
    }
  }
  __syncthreads();
  if (t == 0) {
    stepCnt[vi] = sh_ecnt;
    hasG[vi] = (sh_fcnt > 0);
  }
}

// ---------------------------------------------------------------------------
// k_scan: exclusive prefix over degrees -> row_ptr; resets fillpos to starts.
// ---------------------------------------------------------------------------
__global__ __launch_bounds__(256) void k_scan(int* __restrict__ fillpos,
                                              int* __restrict__ row_ptr) {
  __shared__ int part[256];
  __shared__ int base[257];
  int t = threadIdx.x;
  int v[8];
  int s = 0;
  for (int j = 0; j < 8; j++) { v[j] = fillpos[t * 8 + j]; s += v[j]; }
  part[t] = s;
  __syncthreads();
  if (t == 0) {
    int acc = 0;
    for (int q = 0; q < 256; q++) { base[q] = acc; acc += part[q]; }
    base[256] = acc;
  }
  __syncthreads();
  int acc = base[t];
  for (int j = 0; j < 8; j++) {
    row_ptr[t * 8 + j] = acc;
    fillpos[t * 8 + j] = acc;
    acc += v[j];
  }
  if (t == 255) row_ptr[N] = base[256];
}

// ---------------------------------------------------------------------------
// k_fillB: fused k_fill (blocks 0..127) + k_metaB (blocks 128..128+V-1).
// ---------------------------------------------------------------------------
__global__ __launch_bounds__(256) void k_fillB(
    const int* __restrict__ ei, int E, int* __restrict__ fillpos,
    int* __restrict__ csr_src,
    const int* __restrict__ stepP, const int* __restrict__ stepDm,
    const int* __restrict__ stepCnt, const int* __restrict__ hasG,
    int* __restrict__ entP, int* __restrict__ entPrev, int* __restrict__ entDm,
    int* __restrict__ offsG, int* __restrict__ kidxG, int* __restrict__ cmatG,
    int* __restrict__ lastPG, int* __restrict__ lastIG, int* __restrict__ lastMG,
    int* __restrict__ cntG) {
  __shared__ int pmask[N];           // 8 KB
  __shared__ int sP[16][FCAP];       // 4 KB
  __shared__ int sDm[16][FCAP];      // 4 KB
  __shared__ int cnt[16], offs[17];
  __shared__ int cmat_sh[256];       // 1 KB
  __shared__ int sh_u;
  int t = threadIdx.x;
  if (blockIdx.x < 128) {
    for (int e = blockIdx.x * 256 + t; e < E; e += 128 * 256) {
      int dst = ei[E + e];
      int pos = atomicAdd(&fillpos[dst], 1);
      csr_src[pos] = ei[e];
    }
    return;
  }
  int v = blockIdx.x - 128;
  for (int p = t; p < N; p += 256) pmask[p] = 0;
  for (int x = t; x < 256; x += 256) cmat_sh[x] = 0;
  if (t < 16) cnt[t] = stepCnt[v * L + t];
  if (t == 0) sh_u = 0;
  __syncthreads();
  if (t == 0) {
    int acc = 0;
    for (int i = 0; i < 16; i++) {
      offs[i] = acc < TCAP ? acc : TCAP;
      acc += cnt[i];
    }
    offs[16] = acc < TCAP ? acc : TCAP;
    cntG[v * 2 + 0] = offs[16];
    int k = 0;
    for (int i = 0; i < L; i++) {
      kidxG[v * 16 + i] = k;
      if (hasG[v * L + i]) k++;
    }
  }
  for (int x = t; x < 16 * FCAP; x += 256) {
    int i = x >> 6, f = x & 63;
    if (f < stepCnt[v * L + i]) {
      int p = stepP[(v * L + i) * FCAP + f];
      sP[i][f] = p;
      sDm[i][f] = stepDm[(v * L + i) * FCAP + f];
      atomicOr(&pmask[p], 1 << i);
    }
  }
  __syncthreads();
  for (int x = t; x < 16 * FCAP; x += 256) {
    int i = x >> 6, f = x & 63;
    if (f < cnt[i]) {
      int e = offs[i] + f;
      if (e < TCAP) {
        int p = sP[i][f];
        entP[v * TCAP + e] = p;
        entDm[v * TCAP + e] = sDm[i][f];
        int m = pmask[p] & ((1 << i) - 1);
        int prev = -1;
        if (m) {
          int j = 31 - __clz(m);
          int cj = cnt[j];
          for (int f2 = 0; f2 < cj; f2++)
            if (sP[j][f2] == p) { prev = offs[j] + f2; break; }
        }
        entPrev[v * TCAP + e] = prev;
      }
    }
  }
  __syncthreads();
  for (int p = t; p < N; p += 256) {
    int m = pmask[p];
    if (m) {
      int u = atomicAdd(&sh_u, 1);
      int j = 31 - __clz(m);
      int li = -1;
      int cj = cnt[j];
      for (int f2 = 0; f2 < cj; f2++)
        if (sP[j][f2] == p) { li = offs[j] + f2; break; }
      lastPG[v * TCAP + u] = p;
      lastIG[v * TCAP + u] = li;
      lastMG[v * TCAP + u] = m;
      int mm = m;
      while (mm) {
        int bi = __ffs(mm) - 1; mm &= mm - 1;
        int m2 = m & ((1 << bi) - 1);
        while (m2) {
          int bj = __ffs(m2) - 1; m2 &= m2 - 1;
          atomicAdd(&cmat_sh[bi * 16 + bj], 1);
        }
      }
    }
  }
  __syncthreads();
  if (t == 0) cntG[v * 2 + 1] = sh_u;
  for (int x = t; x < 256; x += 256) cmatG[v * 256 + x] = cmat_sh[x];
  for (int x = t; x < 17; x += 256) offsG[v * 17 + x] = offs[x];
}

// ---------------------------------------------------------------------------
// k_gemm: Z = A @ [W_self|W_nbr]  (M=2048, K=256, N=512), bf16 3-product
// split, fp32 accum.  LDS double-buffered; global prefetch of chunk c+1
// overlaps MFMA of chunk c.  (R0-validated at 377 us total.)
// ---------------------------------------------------------------------------
__global__ __launch_bounds__(256) void k_gemm(
    const ushort* __restrict__ Ah, const ushort* __restrict__ Al,
    const ushort* __restrict__ Wh_g, const ushort* __restrict__ Wl_g,
    float* __restrict__ Z) {
  __shared__ __align__(16) ushort Ash[2][32][72], Asl[2][32][72];
  __shared__ __align__(16) ushort Wsh[2][32][72], Wsl[2][32][72];
  const int tid = threadIdx.x, wave = tid >> 6, lane = tid & 63;
  const int quad = lane >> 4, l16 = lane & 15;
  const int wr = wave >> 1, wc = wave & 1;
  const int mb = blockIdx.x, nb = blockIdx.y;
  const int sr = tid >> 3, sc = (tid & 7) * 8;

  f32x4 acc = {0.f, 0.f, 0.f, 0.f};
  size_t abase = (size_t)mb * 4 * 2048 + (size_t)tid * 8;
  size_t wbase = (size_t)nb * 4 * 2048 + (size_t)tid * 8;
  // stage chunk 0 into buf 0
  {
    uint4 ra  = *(const uint4*)&Ah[abase];
    uint4 rl  = *(const uint4*)&Al[abase];
    uint4 rwh = *(const uint4*)&Wh_g[wbase];
    uint4 rwl = *(const uint4*)&Wl_g[wbase];
    *(uint4*)&Ash[0][sr][sc] = ra;
    *(uint4*)&Asl[0][sr][sc] = rl;
    *(uint4*)&Wsh[0][sr][sc] = rwh;
    *(uint4*)&Wsl[0][sr][sc] = rwl;
  }
  __syncthreads();
#pragma unroll
  for (int c = 0; c < 4; c++) {
    const int rb = c & 1;
    uint4 ra, rl, rwh, rwl;
    if (c < 3) {
      size_t o = (size_t)(c + 1) * 2048;
      ra  = *(const uint4*)&Ah[abase + o];
      rl  = *(const uint4*)&Al[abase + o];
      rwh = *(const uint4*)&Wh_g[wbase + o];
      rwl = *(const uint4*)&Wl_g[wbase + o];
    }
#pragma unroll
    for (int kf = 0; kf < 2; kf++) {
      int ko = kf * 32 + quad * 8;
      bf16x8 a_h = *(const bf16x8*)&Ash[rb][wr * 16 + l16][ko];
      bf16x8 a_l = *(const bf16x8*)&Asl[rb][wr * 16 + l16][ko];
      bf16x8 w_h = *(const bf16x8*)&Wsh[rb][wc * 16 + l16][ko];
      bf16x8 w_l = *(const bf16x8*)&Wsl[rb][wc * 16 + l16][ko];
      acc = __builtin_amdgcn_mfma_f32_16x16x32_bf16(a_h, w_h, acc, 0, 0, 0);
      acc = __builtin_amdgcn_mfma_f32_16x16x32_bf16(a_h, w_l, acc, 0, 0, 0);
      acc = __builtin_amdgcn_mfma_f32_16x16x32_bf16(a_l, w_h, acc, 0, 0, 0);
    }
    if (c < 3) {
      const int wb = rb ^ 1;
      *(uint4*)&Ash[wb][sr][sc] = ra;
      *(uint4*)&Asl[wb][sr][sc] = rl;
      *(uint4*)&Wsh[wb][sr][sc] = rwh;
      *(uint4*)&Wsl[wb][sr][sc] = rwl;
      __syncthreads();
    }
  }
  int col = nb * 32 + wc * 16 + l16;
  int row0 = mb * 32 + wr * 16 + quad * 4;
#pragma unroll
  for (int r = 0; r < 4; r++)
    Z[(size_t)(row0 + r) * 512 + col] = acc[r];
}

// ---------------------------------------------------------------------------
// k_comb: next[r] = relu(Z1[r] + sum_{e in in(r)} Z2[src_e] + b).
// One wave per row; 4-way unrolled gather (4 accumulators, 4 loads in
// flight).  Writes states fp32 + bf16 split of next A (chunked).
// ---------------------------------------------------------------------------
__global__ __launch_bounds__(256) void k_comb(
    const float* __restrict__ Z, const float* __restrict__ bias,
    const int* __restrict__ row_ptr, const int* __restrict__ csr_src,
    float* __restrict__ stnext, ushort* __restrict__ NAh,
    ushort* __restrict__ NAl) {
  int row = blockIdx.x * 4 + (threadIdx.x >> 6);
  int lane = threadIdx.x & 63;
  const float4* Zp = (const float4*)Z;
  float4 acc = Zp[(size_t)row * 128 + lane];            // Z1 self
  float4 acc2 = {0.f, 0.f, 0.f, 0.f};
  float4 acc3 = {0.f, 0.f, 0.f, 0.f};
  float4 acc4 = {0.f, 0.f, 0.f, 0.f};
  int e0 = row_ptr[row], e1 = row_ptr[row + 1];
  int e = e0;
  for (; e + 3 < e1; e += 4) {
    int s0 = csr_src[e], s1 = csr_src[e + 1];
    int s2 = csr_src[e + 2], s3 = csr_src[e + 3];
    float4 x0 = Zp[(size_t)s0 * 128 + 64 + lane];
    float4 x1 = Zp[(size_t)s1 * 128 + 64 + lane];
    float4 x2 = Zp[(size_t)s2 * 128 + 64 + lane];
    float4 x3 = Zp[(size_t)s3 * 128 + 64 + lane];
    acc.x += x0.x; acc.y += x0.y; acc.z += x0.z; acc.w += x0.w;
    acc2.x += x1.x; acc2.y += x1.y; acc2.z += x1.z; acc2.w += x1.w;
    acc3.x += x2.x; acc3.y += x2.y; acc3.z += x2.z; acc3.w += x2.w;
    acc4.x += x3.x; acc4.y += x3.y; acc4.z += x3.z; acc4.w += x3.w;
  }
  for (; e < e1; e++) {
    float4 x0 = Zp[(size_t)csr_src[e] * 128 + 64 + lane];
    acc.x += x0.x; acc.y += x0.y; acc.z += x0.z; acc.w += x0.w;
  }
  float4 bv = ((const float4*)bias)[lane];
  float v0 = fmaxf(acc.x + acc2.x + acc3.x + acc4.x + bv.x, 0.f);
  float v1 = fmaxf(acc.y + acc2.y + acc3.y + acc4.y + bv.y, 0.f);
  float v2 = fmaxf(acc.z + acc2.z + acc3.z + acc4.z + bv.z, 0.f);
  float v3 = fmaxf(acc.w + acc2.w + acc3.w + acc4.w + bv.w, 0.f);
  *(float4*)(stnext + (size_t)row * D + lane * 4) = make_float4(v0, v1, v2, v3);
  ushort h0 = bf16_rn(v0), h1 = bf16_rn(v1), h2 = bf16_rn(v2), h3 = bf16_rn(v3);
  size_t ca = a_addr(row, lane * 4);
  *(ushort4*)&NAh[ca] = make_ushort4(h0, h1, h2, h3);
  *(ushort4*)&NAl[ca] = make_ushort4(
      bf16_rn(v0 - bf16_f(h0)), bf16_rn(v1 - bf16_f(h1)),
      bf16_rn(v2 - bf16_f(h2)), bf16_rn(v3 - bf16_f(h3)));
}

// ---------------------------------------------------------------------------
// k_pi: LINEAR reformulation, 256 threads/block (4 waves).  (validated R2/R3)
// ---------------------------------------------------------------------------
#define PI_LDS_BYTES (TCAP * 64 * 4 + 16 * 64 * 4 + 16 * 64 * 4 + 256 * 4 + \
                      3 * TCAP * 4 + 17 * 4 + 16 * 4 + 256 * 4)
__global__ __launch_bounds__(256) void k_pi(
    const float* __restrict__ states, float* __restrict__ out,
    const int* __restrict__ variants,
    const int* __restrict__ entP, const int* __restrict__ entPrev,
    const int* __restrict__ entDm, const int* __restrict__ offsG,
    const int* __restrict__ kidxG, const int* __restrict__ tlG,
    const int* __restrict__ cmatG, const int* __restrict__ lastPG,
    const int* __restrict__ lastIG, const int* __restrict__ lastMG,
    const int* __restrict__ cntG) {
  extern __shared__ __align__(16) float smf[];
  float* catb = smf;                       // [TCAP][64]  (becomes pref)
  float* S_lds = catb + TCAP * 64;         // [16][64]
  float* aS = S_lds + 16 * 64;             // [16][64] per-step sums
  float* cmatf = aS + 16 * 64;             // [256]
  int* eP  = (int*)(cmatf + 256);          // [TCAP]
  int* ePr = eP + TCAP;
  int* eDm = ePr + TCAP;
  int* offs = eDm + TCAP;                  // [17]
  int* kidx = offs + 17;                   // [16]
  int* tl = kidx + 16;                     // [256]
  int v = blockIdx.x / 12, cgi = blockIdx.x % 12;
  int grp = cgi >> 2;
  int tid = threadIdx.x, lane = tid & 63, w = tid >> 6;
  int cl = (cgi & 3) * 64 + lane;          // 0..255 within third
  int col = cgi * 64 + lane;               // 0..767

  int T = cntG[v * 2 + 0], U = cntG[v * 2 + 1];
  for (int x = tid; x < T; x += 256) {
    eP[x] = entP[v * TCAP + x];
    ePr[x] = entPrev[v * TCAP + x];
    eDm[x] = entDm[v * TCAP + x];
  }
  for (int x = tid; x < 17; x += 256) offs[x] = offsG[v * 17 + x];
  if (tid < 16) kidx[tid] = kidxG[v * 16 + tid];
  for (int x = tid; x < 256; x += 256) {
    tl[x] = tlG[v * 256 + x];
    cmatf[x] = (float)cmatG[v * 256 + x];
  }
  __syncthreads();

  // cat fill: waves split the entries of each step
  for (int i = 0; i < L; i++) {
    int kk = kidx[i]; if (kk > NSTATE - 1) kk = NSTATE - 1;
    const float* embS = states + (size_t)kk * N * D;
    int o0 = offs[i], o1 = offs[i + 1];
    if (grp == 0) {
      for (int e = o0 + w; e < o1; e += 4)
        catb[e * 64 + lane] = embS[(size_t)eP[e] * D + cl];
    } else if (grp == 1) {
      float embA = embS[(size_t)variants[v * L + i] * D + cl];
      for (int e = o0 + w; e < o1; e += 4) catb[e * 64 + lane] = embA;
    } else {
      for (int e = o0 + w; e < o1; e += 4) {
        float sa = 0.f;
        int bm = eDm[e];
        while (bm) {
          int q = __ffs(bm) - 1; bm &= bm - 1;
          sa += embS[(size_t)tl[i * 16 + q] * D + cl];
        }
        catb[e * 64 + lane] = sa;
      }
    }
  }
  __syncthreads();
  // prefix over place-chains, chains distributed across waves
  for (int u = w; u < U; u += 4) {
    int li = lastIG[v * TCAP + u];
    int len = 0;
    for (int c2 = li; c2 >= 0; c2 = ePr[c2]) len++;
    for (int j = 1; j < len; j++) {        // root -> last order
      int c2 = li;
      for (int k = 0; k < len - 1 - j; k++) c2 = ePr[c2];
      catb[c2 * 64 + lane] += catb[ePr[c2] * 64 + lane];
    }
  }
  __syncthreads();
  // per-step sums of pref
  for (int i = w; i < 16; i += 4) {
    float a = 0.f;
    for (int e = offs[i]; e < offs[i + 1]; e++) a += catb[e * 64 + lane];
    aS[i * 64 + lane] = a;
  }
  __syncthreads();
  // S recurrence (serial over 16 steps, wave 0)
  if (w == 0) {
    float S[16];
    float Sp = 0.f;
#pragma unroll
    for (int i = 0; i < 16; i++) {
      float sv = Sp + aS[i * 64 + lane];
#pragma unroll
      for (int j = 0; j < 16; j++)
        if (j < i) sv += cmatf[i * 16 + j] * S[j];
      S[i] = sv;
      S_lds[i * 64 + lane] = sv;
      Sp = sv;
    }
  }
  __syncthreads();
  // outputs, places distributed across waves
  for (int u = w; u < U; u += 4) {
    int p = lastPG[v * TCAP + u];
    int li = lastIG[v * TCAP + u];
    int m = lastMG[v * TCAP + u];
    float acc = catb[li * 64 + lane];
    while (m) {
      int q = __ffs(m) - 1; m &= m - 1;
      acc += S_lds[q * 64 + lane];
    }
    atomicAdd(&out[(size_t)p * C + col], acc);
  }
}

// ---------------------------------------------------------------------------
extern "C" void kernel_launch(void* const* d_in, const int* in_sizes, int n_in,
                              void* d_out, int out_size, void* d_ws, size_t ws_size,
                              hipStream_t stream) {
  const float* emb      = (const float*)d_in[0];
  const float* Ws       = (const float*)d_in[1];
  const float* Wn       = (const float*)d_in[2];
  const float* bias     = (const float*)d_in[3];
  const int*   variants = (const int*)d_in[4];
  const int*   adj      = (const int*)d_in[5];
  const int*   ei       = (const int*)d_in[6];
  const int    E        = in_sizes[6] / 2;
  float* out            = (float*)d_out;

  char* base = (char*)d_ws;
  float* states = (float*)base;            base += (size_t)NSTATE * N * D * 4;
  float* Z      = (float*)base;            base += (size_t)N * 512 * 4;
  ushort* WtHi  = (ushort*)base;           base += (size_t)512 * 256 * 2;
  ushort* WtLo  = (ushort*)base;           base += (size_t)512 * 256 * 2;
  ushort* A0h   = (ushort*)base;           base += (size_t)N * D * 2;
  ushort* A0l   = (ushort*)base;           base += (size_t)N * D * 2;
  ushort* A1h   = (ushort*)base;           base += (size_t)N * D * 2;
  ushort* A1l   = (ushort*)base;           base += (size_t)N * D * 2;
  int* row_ptr  = (int*)base;              base += (N + 1) * 4;
  int* fillpos  = (int*)base;              base += N * 4;
  int* csr_src  = (int*)base;              base += (size_t)E * 4;
  int* stepP    = (int*)base;              base += V * L * FCAP * 4;
  int* stepDm   = (int*)base;              base += V * L * FCAP * 4;
  int* stepCnt  = (int*)base;              base += V * L * 4;
  int* hasG     = (int*)base;              base += V * L * 4;
  int* entP     = (int*)base;              base += V * TCAP * 4;
  int* entPrev  = (int*)base;              base += V * TCAP * 4;
  int* entDm    = (int*)base;              base += V * TCAP * 4;
  int* offsG    = (int*)base;              base += V * 17 * 4;
  int* kidxG    = (int*)base;              base += V * 16 * 4;
  int* tlG      = (int*)base;              base += V * 256 * 4;
  int* cmatG    = (int*)base;              base += V * 256 * 4;
  int* lastPG   = (int*)base;              base += V * TCAP * 4;
  int* lastIG   = (int*)base;              base += V * TCAP * 4;
  int* lastMG   = (int*)base;              base += V * TCAP * 4;
  int* cntG     = (int*)base;              base += V * 2 * 4;

  hipFuncSetAttribute((const void*)k_pi,
                      hipFuncAttributeMaxDynamicSharedMemorySize, PI_LDS_BYTES);

  k_init<<<512, 256, 0, stream>>>(emb, Ws, Wn, states, WtHi, WtLo, A0h, A0l,
                                  out, fillpos);
  k_degA<<<128 + V * L, 256, 0, stream>>>(ei, E, fillpos, adj, variants,
                                          stepP, stepDm, stepCnt, hasG, tlG);
  k_scan<<<1, 256, 0, stream>>>(fillpos, row_ptr);
  k_fillB<<<128 + V, 256, 0, stream>>>(ei, E, fillpos, csr_src, stepP, stepDm,
                                       stepCnt, hasG, entP, entPrev, entDm,
                                       offsG, kidxG, cmatG, lastPG, lastIG,
                                       lastMG, cntG);

  ushort* AH[2] = {A0h, A1h};
  ushort* AL[2] = {A0l, A1l};
  for (int s = 0; s < NAPP; s++) {
    int cur = s & 1, nxt = cur ^ 1;
    k_gemm<<<dim3(64, 16), 256, 0, stream>>>(AH[cur], AL[cur], WtHi, WtLo, Z);
    k_comb<<<N / 4, 256, 0, stream>>>(Z, bias, row_ptr, csr_src,
                                      states + (size_t)(s + 1) * N * D,
                                      AH[nxt], AL[nxt]);
  }
  k_pi<<<V * 12, 256, PI_LDS_BYTES, stream>>>(states, out, variants, entP,
                                              entPrev, entDm, offsG, kidxG, tlG,
                                              cmatG, lastPG, lastIG, lastMG,
                                              cntG);
}